// Round 16
// baseline (2038.469 us; speedup 1.0000x reference)
//
#include <hip/hip_runtime.h>

// FFJORD B=4096 D=64 C=16 H=512, NBIJ=2, NSTEPS=8 RK4 -> 64 sequential MLP+VJP evals.
// Round 22: R21 (delayed-issue ring) = 957us. Still latency-bound (MFMA 8%, VALU 18%,
// HBM 1.3%); cost is the 4-barrier phase structure (36K cy/eval vs 3.4K MFMA). This
// round deletes the P3 phase: GEMM3f re-split along OWN columns - wave w computes
// f_partial over n in its slice [32w,32w+32), i.e. the h2 values the wave itself wrote
// in P2's epilogue -> within-wave LDS write->read, NO cross-wave dep, NO barrier.
// K=32 x 4 d-tiles, A = one short8 readback, B = same W3f bytes, 4 MFMA + 16 f_s
// atomics (was 4). Panel prefetch rides P2 epilogue. Barriers 4 -> 3 per eval.

typedef __attribute__((ext_vector_type(8))) short short8;
typedef __attribute__((ext_vector_type(4))) float f32x4;
typedef __attribute__((ext_vector_type(4))) int int4v;

#define MFMA_B16(a, b, c) __builtin_amdgcn_mfma_f32_16x16x32_bf16((a), (b), (c), 0, 0, 0)
#define MFMA_I8(a, b, c)  __builtin_amdgcn_mfma_i32_16x16x64_i8((a), (b), (c), 0, 0, 0)

__device__ __forceinline__ unsigned short f2bf(float f) {
  union { float f; unsigned u; } v; v.f = f;
  return (unsigned short)((v.u + 0x7FFFu + ((v.u >> 16) & 1u)) >> 16);
}
__device__ __forceinline__ float bf2f(unsigned short u) {
  union { unsigned u; float f; } v; v.u = ((unsigned)u) << 16; return v.f;
}
__device__ __forceinline__ float fast_tanh(float x) {
  float e = __expf(2.f * x);
  return 1.f - 2.f * __builtin_amdgcn_rcpf(e + 1.f);
}

// ws layout:
// W1f  bf16 [2][512][96]       @ ush 0       (k>=81 zero-padded)
// W2f8 i8   [2][8p][512n][64k] @ byte 196608 (W2^T tiles; byte kk stores
//                                             k = p*64 + (kk ^ ((n>>1&3)<<4)))
// W3f  bf16 [2][64][512]       @ ush 360448  (W3^T: B for f = h2 @ W3)
// W3b  bf16 [2][512][64]       @ ush 425984  (plain W3: B for e3 = eps @ W3^T)
// W1u  bf16 [2][512][64]       @ ush 491520  (W1u[h][d] = W1[d][h]: B for u = eps @ W1y)
// sc   f32  [2][512]           @ byte 1114112 (colmax_n |W2[:,n]|)

__global__ void prep_scales(const float* __restrict__ W2, float* __restrict__ sc) {
  int idx = blockIdx.x * 256 + threadIdx.x;
  if (idx >= 1024) return;
  int ib = idx >> 9, n = idx & 511;
  const float* W = W2 + (size_t)ib * 262144;
  float m = 0.f;
  for (int k = 0; k < 512; ++k) m = fmaxf(m, fabsf(W[(size_t)k * 512 + n]));
  sc[idx] = fmaxf(m, 1e-8f);
}

__global__ void prep_bf16(const float* __restrict__ W1, const float* __restrict__ W2,
                          const float* __restrict__ W3, unsigned short* __restrict__ ws) {
  int o = blockIdx.x * 256 + threadIdx.x;
  char* ws8 = (char*)ws;
  const float* sc = (const float*)(ws8 + 1114112);
  if (o < 98304) {
    int ib = o / 49152, r = o % 49152, n = r / 96, k = r % 96;
    ws[o] = (k < 81) ? f2bf(W1[(size_t)ib * 41472 + k * 512 + n]) : (unsigned short)0;
  } else if (o < 622592) {
    int b = o - 98304;
    int ib = b / 262144, b2 = b % 262144;
    int p = b2 / 32768, r2 = b2 % 32768, n = r2 / 64, kk = r2 & 63;
    int k = p * 64 + (kk ^ (((n >> 1) & 3) << 4));
    float w = W2[(size_t)ib * 262144 + (size_t)k * 512 + n];
    float s = sc[ib * 512 + n];
    int q = (int)rintf(w * (127.f / s));
    q = q > 127 ? 127 : (q < -127 ? -127 : q);
    ws8[196608 + b] = (char)q;
  } else if (o < 688128) {
    int o2 = o - 622592;
    int ib = o2 / 32768, r = o2 % 32768, n = r / 512, k = r % 512;
    ws[360448 + o2] = f2bf(W3[(size_t)ib * 32768 + k * 64 + n]);
  } else if (o < 753664) {
    int o2 = o - 688128;
    ws[425984 + o2] = f2bf(W3[o2]);
  } else if (o < 819200) {
    int o2 = o - 753664;
    int ib = o2 / 32768, r = o2 % 32768, h = r / 64, d = r % 64;
    ws[491520 + o2] = f2bf(W1[(size_t)ib * 41472 + d * 512 + h]);
  }
}

#define ZS 104    // z A-buffer stride, ush (K=96 used; also hosts eps for e3/u GEMMs)
#define HS 520    // bf16 h2 buffer stride, ush
#define H8 528    // i8 h1/v buffer stride, bytes
#define INV2 (1.f / 16129.f)   // 1/(127*127)

// Per-wave async stage of one 2KB slice (own 32 rows x 64 bytes) of a 32KB i8 panel.
#define ISSUE_STAGE(WP, KS, BUF) do {                                                   \
    const char* _s = (WP) + (KS) * 32768 + (wave << 11) + (lane << 4);                  \
    char* _d = &Bst[(BUF)][wave << 11];                                                 \
    __builtin_amdgcn_global_load_lds(                                                   \
        (const __attribute__((address_space(1))) void*)_s,                              \
        (__attribute__((address_space(3))) void*)_d, 16, 0, 0);                         \
    __builtin_amdgcn_global_load_lds(                                                   \
        (const __attribute__((address_space(1))) void*)(_s + 1024),                     \
        (__attribute__((address_space(3))) void*)(_d + 1024), 16, 0, 0);                \
  } while (0)

__global__ __launch_bounds__(1024) void ffjord_mfma(
    const float* __restrict__ x, const float* __restrict__ cond, const float* __restrict__ eps,
    const float* __restrict__ b1g, const float* __restrict__ b2g, const float* __restrict__ b3g,
    const unsigned short* __restrict__ ws, float* __restrict__ out) {
  __shared__ unsigned short zA[16 * ZS];
  __shared__ __align__(16) char h1A8[16 * H8];   // h1 as i8 (q = round(h1*127))
  __shared__ __align__(16) char vA8[16 * H8];    // v = (1-h1^2)*u as i8 (scale su[m])
  __shared__ unsigned short h2A[16 * HS];        // h2 bf16 (f-GEMM A-operand)
  __shared__ __align__(16) char Bst[3][32768];   // staging ring: 3 x 32KB i8 panels
  __shared__ float f_s[16][64];
  __shared__ float l_row[16], ld_row[16], ldacc[16];
  __shared__ int sgu[16];                        // per-bijector rowmax |u| bits

  const int t = threadIdx.x;
  const int wave = t >> 6;
  const int lane = t & 63;
  const int lane15 = lane & 15;
  const int q8 = (lane >> 4) * 8;        // bf16 frag k-offset
  const int q16 = (lane >> 4) * 16;      // i8 frag k-offset (bytes)
  const int rowb = q8 >> 1;              // C/D row base
  const int row0 = blockIdx.x * 16;
  const int ws32 = wave * 32;            // N-slice base for N=512 GEMMs
  const int tm = t >> 6, td = t & 63;    // (row, dim) element owned by this thread

  // swizzled 16B-granule read offset (same XOR for rows lane15 and 16+lane15)
  const int kk2b = q16 ^ (((lane15 >> 1) & 3) << 4);

  // RK4 state in registers (thread-private)
  float ycur, ytmp, yacc = 0.f;
  {
    float xv = x[(size_t)(row0 + tm) * 64 + td];
    ycur = xv; ytmp = xv;
  }
  if (t < 512) {
    int m = t >> 5, kk = t & 31;
    zA[m * ZS + 64 + kk] = (kk < 16) ? f2bf(cond[(size_t)(row0 + m) * 16 + kk]) : (unsigned short)0;
  }
  if (t < 16) { ld_row[t] = 0.f; l_row[t] = 0.f; }

  const float dt = 0.125f;
  const float w06 = dt / 6.f, w13 = dt / 3.f;
  const char* wsb = (const char*)ws;

  for (int ib = 0; ib < 2; ++ib) {
    const unsigned short* W1f = ws + ib * 49152;
    const char* W2f8 = wsb + 196608 + ib * 262144;
    const unsigned short* W3f = ws + 360448 + ib * 32768;
    const unsigned short* W3b = ws + 425984 + ib * 32768;
    const unsigned short* W1u = ws + 491520 + ib * 32768;
    const float* scf = (const float*)(wsb + 1114112) + ib * 512;
    const float* b1b = b1g + ib * 512;
    const float* b2b = b2g + ib * 512;
    const float* b3b = b3g + ib * 64;

    // ---- bijector prologue: stage eps (bf16, borrow zA), e3 + u GEMMs ----
    zA[tm * ZS + td] = f2bf(eps[((size_t)ib * 4096 + row0 + tm) * 64 + td]);
    if (t < 16) sgu[t] = 0;
    __syncthreads();

    float e3r[8], ur[8];
    {
      f32x4 a0 = {0,0,0,0}, a1 = {0,0,0,0};   // e3 = eps @ W3^T
      f32x4 u0 = {0,0,0,0}, u1 = {0,0,0,0};   // u  = eps @ W1y
      const unsigned short* ap = zA + lane15 * ZS + q8;
      const unsigned short* wp3 = W3b + (size_t)(ws32 + lane15) * 64 + q8;
      const unsigned short* wpu = W1u + (size_t)(ws32 + lane15) * 64 + q8;
      #pragma unroll
      for (int kk = 0; kk < 64; kk += 32) {
        short8 a = *(const short8*)(ap + kk);
        a0 = MFMA_B16(a, *(const short8*)(wp3 + kk),           a0);
        a1 = MFMA_B16(a, *(const short8*)(wp3 + 16 * 64 + kk), a1);
        u0 = MFMA_B16(a, *(const short8*)(wpu + kk),           u0);
        u1 = MFMA_B16(a, *(const short8*)(wpu + 16 * 64 + kk), u1);
      }
      #pragma unroll
      for (int rg = 0; rg < 4; ++rg) {
        e3r[rg] = a0[rg]; e3r[4 + rg] = a1[rg];
        ur[rg] = u0[rg];  ur[4 + rg] = u1[rg];
      }
      // per-row max|u| (exact per-bijector bound for the v quantization)
      #pragma unroll
      for (int rg = 0; rg < 4; ++rg) {
        float mr = fmaxf(fabsf(ur[rg]), fabsf(ur[4 + rg]));
        #pragma unroll
        for (int o = 1; o < 16; o <<= 1) mr = fmaxf(mr, __shfl_xor(mr, o));
        if (lane15 == 0) atomicMax(&sgu[rowb + rg], __float_as_int(mr));
      }
    }
    __syncthreads();   // sgu complete; zA about to be rewritten by P0

    float su_[4], qsv[4];
    #pragma unroll
    for (int rg = 0; rg < 4; ++rg) {
      float sg = fmaxf(__int_as_float(sgu[rowb + rg]), 1e-20f);
      su_[rg] = sg * INV2;       // folded w-dequant factor (x scf[n] later)
      qsv[rg] = 127.f / sg;
    }

    for (int it = 0; it < 32; ++it) {
      const int s = it & 3;
      const float te = (it >> 2) * dt + ((s == 0) ? 0.f : (s == 3) ? dt : 0.5f * dt);

      // ---- P0: deferred RK4 + logdet, z build, zero f_s; it==0: prefetch 2 panels ----
      if (it > 0) {
        int sp = (it - 1) & 3;
        float fv = f_s[tm][td] + b3b[td];
        if (sp == 0)      { yacc = ycur + w06 * fv; ytmp = ycur + 0.5f * dt * fv; }
        else if (sp == 1) { yacc += w13 * fv;       ytmp = ycur + 0.5f * dt * fv; }
        else if (sp == 2) { yacc += w13 * fv;       ytmp = ycur + dt * fv; }
        else              { float yn = yacc + w06 * fv; ycur = yn; ytmp = yn; }
      }
      zA[tm * ZS + td] = f2bf(ytmp);
      f_s[tm][td] = 0.f;
      if (t < 16) {
        if (it > 0) {
          int sp = (it - 1) & 3;
          float lv = l_row[t];
          if (sp == 0)      ldacc[t] = w06 * lv;
          else if (sp < 3)  ldacc[t] += w13 * lv;
          else              ld_row[t] += ldacc[t] + w06 * lv;
        }
        l_row[t] = 0.f;
        zA[t * ZS + 80] = f2bf(te);
      }
      if (it == 0) { ISSUE_STAGE(W2f8, 0, 0); ISSUE_STAGE(W2f8, 1, 1); }
      __syncthreads();

      // ---- P1: GEMM1 (bf16): h1 = tanh(z @ W1 + b1); store h1 i8 and v i8 ----
      {
        f32x4 a0 = {0,0,0,0}, a1 = {0,0,0,0};
        const unsigned short* ap = zA + lane15 * ZS + q8;
        const unsigned short* wp = W1f + (size_t)(ws32 + lane15) * 96 + q8;
        #pragma unroll
        for (int k0 = 0; k0 < 96; k0 += 32) {
          short8 a = *(const short8*)(ap + k0);
          a0 = MFMA_B16(a, *(const short8*)(wp + k0),           a0);
          a1 = MFMA_B16(a, *(const short8*)(wp + 16 * 96 + k0), a1);
        }
        #pragma unroll
        for (int tl = 0; tl < 2; ++tl) {
          int n = ws32 + tl * 16 + lane15;
          float bias = b1b[n];
          f32x4 ac = tl ? a1 : a0;
          #pragma unroll
          for (int rg = 0; rg < 4; ++rg) {
            float th = fast_tanh(ac[rg] + bias);
            int off = (rowb + rg) * H8 + n;
            h1A8[off] = (char)__float2int_rn(th * 127.f);
            float v = (1.f - th * th) * ur[tl * 4 + rg];
            vA8[off] = (char)__float2int_rn(v * qsv[rg]);
          }
        }
      }
      __syncthreads();

      // ---- P2: staged dual i8 GEMM + epilogue + own-column f-GEMM (no P3 phase) ----
      {
        int4v ha0 = {0,0,0,0}, ha1 = {0,0,0,0}, wa0 = {0,0,0,0}, wa1 = {0,0,0,0};
        const char* aph = h1A8 + lane15 * H8;
        const char* apv = vA8 + lane15 * H8;
        #pragma unroll
        for (int ks = 0; ks < 8; ++ks) {
          // wait panel ks landed: newest pair in flight is p_{ks+1}; at ks=7 drain all
          if (ks < 7) asm volatile("s_waitcnt vmcnt(2)" ::: "memory");
          else        asm volatile("s_waitcnt vmcnt(0)" ::: "memory");
          const char* bq = &Bst[ks % 3][wave << 11];
          int4v ah = *(const int4v*)(aph + ks * 64 + q16);
          int4v av = *(const int4v*)(apv + ks * 64 + q16);
          int4v b0 = *(const int4v*)(bq + lane15 * 64 + kk2b);
          int4v b1 = *(const int4v*)(bq + (16 + lane15) * 64 + kk2b);
          if (ks < 6) {
            // WAR guard: slot (ks+2)%3 == (ks-1)%3 was read LAST iteration; DS retires
            // in-order, so lgkmcnt(4) (this iteration's 4 reads may remain) suffices.
            asm volatile("s_waitcnt lgkmcnt(4)" ::: "memory");
            ISSUE_STAGE(W2f8, ks + 2, (ks + 2) % 3);
          }
          ha0 = MFMA_I8(ah, b0, ha0);
          ha1 = MFMA_I8(ah, b1, ha1);
          wa0 = MFMA_I8(av, b0, wa0);
          wa1 = MFMA_I8(av, b1, wa1);
        }
        float p0 = 0.f, p1 = 0.f, p2 = 0.f, p3 = 0.f;
        #pragma unroll
        for (int tl = 0; tl < 2; ++tl) {
          int n = ws32 + tl * 16 + lane15;
          float bias = b2b[n];
          float dq = scf[n] * INV2;
          float dqw = scf[n];
          int4v hac = tl ? ha1 : ha0;
          int4v wac = tl ? wa1 : wa0;
          #pragma unroll
          for (int rg = 0; rg < 4; ++rg) {
            float h = fast_tanh((float)hac[rg] * dq + bias);
            h2A[(rowb + rg) * HS + n] = f2bf(h);
            float g2 = e3r[tl * 4 + rg] * (1.f - h * h);
            float w = (float)wac[rg] * dqw * su_[rg];
            float pc = g2 * w;
            if (rg == 0) p0 += pc; else if (rg == 1) p1 += pc;
            else if (rg == 2) p2 += pc; else p3 += pc;
          }
        }
        // prefetch next-eval panels 0,1 (latency hides under f-GEMM + reductions)
        if (it < 31) { ISSUE_STAGE(W2f8, 0, 0); ISSUE_STAGE(W2f8, 1, 1); }
        // own-column f-GEMM: f_partial[m][d] = sum_{n in own slice} h2[m][n] W3[n][d].
        // A = h2A rows 0..15 at cols ws32..ws32+32 -- written by THIS wave above
        // (its lanes cover all 16 rows of its 32-col slice); within-wave LDS
        // write->read, compiler orders via lgkmcnt. K=32, 4 d-tiles, 1 MFMA each.
        {
          const unsigned short* ap3 = h2A + lane15 * HS + ws32 + q8;
          const unsigned short* wpb = W3f + (size_t)lane15 * 512 + ws32 + q8;
          short8 afrag = *(const short8*)ap3;
          #pragma unroll
          for (int tile = 0; tile < 4; ++tile) {
            f32x4 c = {0,0,0,0};
            c = MFMA_B16(afrag, *(const short8*)(wpb + (size_t)tile * 16 * 512), c);
            #pragma unroll
            for (int rg = 0; rg < 4; ++rg)
              atomicAdd(&f_s[rowb + rg][tile * 16 + lane15], c[rg]);
          }
        }
        #pragma unroll
        for (int o = 1; o < 16; o <<= 1) {
          p0 += __shfl_xor(p0, o); p1 += __shfl_xor(p1, o);
          p2 += __shfl_xor(p2, o); p3 += __shfl_xor(p3, o);
        }
        if (lane15 == 0) {
          atomicAdd(&l_row[rowb + 0], p0); atomicAdd(&l_row[rowb + 1], p1);
          atomicAdd(&l_row[rowb + 2], p2); atomicAdd(&l_row[rowb + 3], p3);
        }
      }
      __syncthreads();
    }

    // ---- bijector finalize: last RK4 stage (s=3) + logdet stage ----
    {
      float fv = f_s[tm][td] + b3b[td];
      float yn = yacc + w06 * fv;
      ycur = yn; ytmp = yn;
    }
    if (t < 16) { ld_row[t] += ldacc[t] + w06 * l_row[t]; l_row[t] = 0.f; }
    __syncthreads();
  }

  out[(size_t)(row0 + tm) * 65 + td] = ycur;
  if (t < 16) out[(size_t)(row0 + t) * 65 + 64] = ld_row[t];
}

extern "C" void kernel_launch(void* const* d_in, const int* in_sizes, int n_in,
                              void* d_out, int out_size, void* d_ws, size_t ws_size,
                              hipStream_t stream) {
  (void)in_sizes; (void)n_in; (void)out_size; (void)ws_size;
  const float* x    = (const float*)d_in[0];
  const float* cond = (const float*)d_in[1];
  const float* eps  = (const float*)d_in[2];
  const float* W1   = (const float*)d_in[3];
  const float* b1   = (const float*)d_in[4];
  const float* W2   = (const float*)d_in[5];
  const float* b2   = (const float*)d_in[6];
  const float* W3   = (const float*)d_in[7];
  const float* b3   = (const float*)d_in[8];
  float* out = (float*)d_out;
  unsigned short* ws = (unsigned short*)d_ws;

  prep_scales<<<4, 256, 0, stream>>>(W2, (float*)((char*)ws + 1114112));
  const int prep_total = 819200;
  prep_bf16<<<(prep_total + 255) / 256, 256, 0, stream>>>(W1, W2, W3, ws);
  ffjord_mfma<<<256, 1024, 0, stream>>>(x, cond, eps, b1, b2, b3, ws, out);
}

// Round 18
// 1046.778 us; speedup vs baseline: 1.9474x; 1.9474x over previous
//
#include <hip/hip_runtime.h>

// FFJORD B=4096 D=64 C=16 H=512, NBIJ=2, NSTEPS=8 RK4 -> 64 sequential MLP+VJP evals.
// Round 24 = Round 23 resubmitted verbatim (container infra failure, no kernel verdict).
// R22 (own-column f-GEMM) regressed -> reverted to R21. Single change vs R21: the three
// per-eval __syncthreads (vmcnt(0)+lgkmcnt(0) drains) become {lgkmcnt(0); s_barrier} --
// next-eval panel prefetches issued in P2/P3 stay IN FLIGHT across barriers; their L2
// latency hides under P0+P1 (T4: never vmcnt(0) at a main-loop barrier). Correctness:
// cross-wave deps are all DS ops (zA/h1A8/vA8/h2A writes, f_s/l_row atomics) ordered by
// lgkmcnt(0); staging ring is wave-private and paced by counted vmcnt(2) (older
// interleaved loads retire first -> wait only gets stricter).

typedef __attribute__((ext_vector_type(8))) short short8;
typedef __attribute__((ext_vector_type(4))) float f32x4;
typedef __attribute__((ext_vector_type(4))) int int4v;

#define MFMA_B16(a, b, c) __builtin_amdgcn_mfma_f32_16x16x32_bf16((a), (b), (c), 0, 0, 0)
#define MFMA_I8(a, b, c)  __builtin_amdgcn_mfma_i32_16x16x64_i8((a), (b), (c), 0, 0, 0)

__device__ __forceinline__ unsigned short f2bf(float f) {
  union { float f; unsigned u; } v; v.f = f;
  return (unsigned short)((v.u + 0x7FFFu + ((v.u >> 16) & 1u)) >> 16);
}
__device__ __forceinline__ float bf2f(unsigned short u) {
  union { unsigned u; float f; } v; v.u = ((unsigned)u) << 16; return v.f;
}
__device__ __forceinline__ float fast_tanh(float x) {
  float e = __expf(2.f * x);
  return 1.f - 2.f * __builtin_amdgcn_rcpf(e + 1.f);
}

// Relaxed phase barrier: order DS ops (cross-wave visibility) but leave global_load_lds
// panel prefetches in flight (tracked by the K-loop's counted vmcnt).
#define PHASE_BARRIER() do {                                \
    asm volatile("s_waitcnt lgkmcnt(0)" ::: "memory");      \
    __builtin_amdgcn_s_barrier();                           \
  } while (0)

// ws layout:
// W1f  bf16 [2][512][96]       @ ush 0       (k>=81 zero-padded)
// W2f8 i8   [2][8p][512n][64k] @ byte 196608 (W2^T tiles; byte kk stores
//                                             k = p*64 + (kk ^ ((n>>1&3)<<4)))
// W3f  bf16 [2][64][512]       @ ush 360448  (W3^T: B for f = h2 @ W3)
// W3b  bf16 [2][512][64]       @ ush 425984  (plain W3: B for e3 = eps @ W3^T)
// W1u  bf16 [2][512][64]       @ ush 491520  (W1u[h][d] = W1[d][h]: B for u = eps @ W1y)
// sc   f32  [2][512]           @ byte 1114112 (colmax_n |W2[:,n]|)

__global__ void prep_scales(const float* __restrict__ W2, float* __restrict__ sc) {
  int idx = blockIdx.x * 256 + threadIdx.x;
  if (idx >= 1024) return;
  int ib = idx >> 9, n = idx & 511;
  const float* W = W2 + (size_t)ib * 262144;
  float m = 0.f;
  for (int k = 0; k < 512; ++k) m = fmaxf(m, fabsf(W[(size_t)k * 512 + n]));
  sc[idx] = fmaxf(m, 1e-8f);
}

__global__ void prep_bf16(const float* __restrict__ W1, const float* __restrict__ W2,
                          const float* __restrict__ W3, unsigned short* __restrict__ ws) {
  int o = blockIdx.x * 256 + threadIdx.x;
  char* ws8 = (char*)ws;
  const float* sc = (const float*)(ws8 + 1114112);
  if (o < 98304) {
    int ib = o / 49152, r = o % 49152, n = r / 96, k = r % 96;
    ws[o] = (k < 81) ? f2bf(W1[(size_t)ib * 41472 + k * 512 + n]) : (unsigned short)0;
  } else if (o < 622592) {
    int b = o - 98304;
    int ib = b / 262144, b2 = b % 262144;
    int p = b2 / 32768, r2 = b2 % 32768, n = r2 / 64, kk = r2 & 63;
    int k = p * 64 + (kk ^ (((n >> 1) & 3) << 4));
    float w = W2[(size_t)ib * 262144 + (size_t)k * 512 + n];
    float s = sc[ib * 512 + n];
    int q = (int)rintf(w * (127.f / s));
    q = q > 127 ? 127 : (q < -127 ? -127 : q);
    ws8[196608 + b] = (char)q;
  } else if (o < 688128) {
    int o2 = o - 622592;
    int ib = o2 / 32768, r = o2 % 32768, n = r / 512, k = r % 512;
    ws[360448 + o2] = f2bf(W3[(size_t)ib * 32768 + k * 64 + n]);
  } else if (o < 753664) {
    int o2 = o - 688128;
    ws[425984 + o2] = f2bf(W3[o2]);
  } else if (o < 819200) {
    int o2 = o - 753664;
    int ib = o2 / 32768, r = o2 % 32768, h = r / 64, d = r % 64;
    ws[491520 + o2] = f2bf(W1[(size_t)ib * 41472 + d * 512 + h]);
  }
}

#define ZS 104    // z A-buffer stride, ush (K=96 used; also hosts eps for e3/u GEMMs)
#define HS 520    // bf16 h2 buffer stride, ush
#define H8 528    // i8 h1/v buffer stride, bytes
#define INV2 (1.f / 16129.f)   // 1/(127*127)

// Per-wave async stage of one 2KB slice (own 32 rows x 64 bytes) of a 32KB i8 panel.
#define ISSUE_STAGE(WP, KS, BUF) do {                                                   \
    const char* _s = (WP) + (KS) * 32768 + (wave << 11) + (lane << 4);                  \
    char* _d = &Bst[(BUF)][wave << 11];                                                 \
    __builtin_amdgcn_global_load_lds(                                                   \
        (const __attribute__((address_space(1))) void*)_s,                              \
        (__attribute__((address_space(3))) void*)_d, 16, 0, 0);                         \
    __builtin_amdgcn_global_load_lds(                                                   \
        (const __attribute__((address_space(1))) void*)(_s + 1024),                     \
        (__attribute__((address_space(3))) void*)(_d + 1024), 16, 0, 0);                \
  } while (0)

__global__ __launch_bounds__(1024) void ffjord_mfma(
    const float* __restrict__ x, const float* __restrict__ cond, const float* __restrict__ eps,
    const float* __restrict__ b1g, const float* __restrict__ b2g, const float* __restrict__ b3g,
    const unsigned short* __restrict__ ws, float* __restrict__ out) {
  __shared__ unsigned short zA[16 * ZS];
  __shared__ __align__(16) char h1A8[16 * H8];   // h1 as i8 (q = round(h1*127))
  __shared__ __align__(16) char vA8[16 * H8];    // v = (1-h1^2)*u as i8 (scale su[m])
  __shared__ unsigned short h2A[16 * HS];        // h2 bf16 (GEMM3f A-operand)
  __shared__ __align__(16) char Bst[3][32768];   // staging ring: 3 x 32KB i8 panels
  __shared__ float f_s[16][64];
  __shared__ float l_row[16], ld_row[16], ldacc[16];
  __shared__ int sgu[16];                        // per-bijector rowmax |u| bits

  const int t = threadIdx.x;
  const int wave = t >> 6;
  const int lane = t & 63;
  const int lane15 = lane & 15;
  const int q8 = (lane >> 4) * 8;        // bf16 frag k-offset
  const int q16 = (lane >> 4) * 16;      // i8 frag k-offset (bytes)
  const int rowb = q8 >> 1;              // C/D row base
  const int row0 = blockIdx.x * 16;
  const int ws32 = wave * 32;            // N-slice base for N=512 GEMMs
  const int nt3 = wave & 3;              // N-tile for GEMM3f
  const int kb3 = (wave >> 2) * 128;     // K-slice base for GEMM3f
  const int tm = t >> 6, td = t & 63;    // (row, dim) element owned by this thread

  // swizzled 16B-granule read offset (same XOR for rows lane15 and 16+lane15)
  const int kk2b = q16 ^ (((lane15 >> 1) & 3) << 4);

  // RK4 state in registers (thread-private)
  float ycur, ytmp, yacc = 0.f;
  {
    float xv = x[(size_t)(row0 + tm) * 64 + td];
    ycur = xv; ytmp = xv;
  }
  if (t < 512) {
    int m = t >> 5, kk = t & 31;
    zA[m * ZS + 64 + kk] = (kk < 16) ? f2bf(cond[(size_t)(row0 + m) * 16 + kk]) : (unsigned short)0;
  }
  if (t < 16) { ld_row[t] = 0.f; l_row[t] = 0.f; }

  const float dt = 0.125f;
  const float w06 = dt / 6.f, w13 = dt / 3.f;
  const char* wsb = (const char*)ws;

  for (int ib = 0; ib < 2; ++ib) {
    const unsigned short* W1f = ws + ib * 49152;
    const char* W2f8 = wsb + 196608 + ib * 262144;
    const unsigned short* W3f = ws + 360448 + ib * 32768;
    const unsigned short* W3b = ws + 425984 + ib * 32768;
    const unsigned short* W1u = ws + 491520 + ib * 32768;
    const float* scf = (const float*)(wsb + 1114112) + ib * 512;
    const float* b1b = b1g + ib * 512;
    const float* b2b = b2g + ib * 512;
    const float* b3b = b3g + ib * 64;

    // ---- bijector prologue: stage eps (bf16, borrow zA), e3 + u GEMMs ----
    zA[tm * ZS + td] = f2bf(eps[((size_t)ib * 4096 + row0 + tm) * 64 + td]);
    if (t < 16) sgu[t] = 0;
    __syncthreads();

    float e3r[8], ur[8];
    {
      f32x4 a0 = {0,0,0,0}, a1 = {0,0,0,0};   // e3 = eps @ W3^T
      f32x4 u0 = {0,0,0,0}, u1 = {0,0,0,0};   // u  = eps @ W1y
      const unsigned short* ap = zA + lane15 * ZS + q8;
      const unsigned short* wp3 = W3b + (size_t)(ws32 + lane15) * 64 + q8;
      const unsigned short* wpu = W1u + (size_t)(ws32 + lane15) * 64 + q8;
      #pragma unroll
      for (int kk = 0; kk < 64; kk += 32) {
        short8 a = *(const short8*)(ap + kk);
        a0 = MFMA_B16(a, *(const short8*)(wp3 + kk),           a0);
        a1 = MFMA_B16(a, *(const short8*)(wp3 + 16 * 64 + kk), a1);
        u0 = MFMA_B16(a, *(const short8*)(wpu + kk),           u0);
        u1 = MFMA_B16(a, *(const short8*)(wpu + 16 * 64 + kk), u1);
      }
      #pragma unroll
      for (int rg = 0; rg < 4; ++rg) {
        e3r[rg] = a0[rg]; e3r[4 + rg] = a1[rg];
        ur[rg] = u0[rg];  ur[4 + rg] = u1[rg];
      }
      // per-row max|u| (exact per-bijector bound for the v quantization)
      #pragma unroll
      for (int rg = 0; rg < 4; ++rg) {
        float mr = fmaxf(fabsf(ur[rg]), fabsf(ur[4 + rg]));
        #pragma unroll
        for (int o = 1; o < 16; o <<= 1) mr = fmaxf(mr, __shfl_xor(mr, o));
        if (lane15 == 0) atomicMax(&sgu[rowb + rg], __float_as_int(mr));
      }
    }
    __syncthreads();   // sgu complete; zA about to be rewritten by P0

    float su_[4], qsv[4];
    #pragma unroll
    for (int rg = 0; rg < 4; ++rg) {
      float sg = fmaxf(__int_as_float(sgu[rowb + rg]), 1e-20f);
      su_[rg] = sg * INV2;       // folded w-dequant factor (x scf[n] later)
      qsv[rg] = 127.f / sg;
    }

    for (int it = 0; it < 32; ++it) {
      const int s = it & 3;
      const float te = (it >> 2) * dt + ((s == 0) ? 0.f : (s == 3) ? dt : 0.5f * dt);

      // ---- P0: deferred RK4 + logdet, z build, zero f_s; it==0: prefetch 2 panels ----
      if (it > 0) {
        int sp = (it - 1) & 3;
        float fv = f_s[tm][td] + b3b[td];
        if (sp == 0)      { yacc = ycur + w06 * fv; ytmp = ycur + 0.5f * dt * fv; }
        else if (sp == 1) { yacc += w13 * fv;       ytmp = ycur + 0.5f * dt * fv; }
        else if (sp == 2) { yacc += w13 * fv;       ytmp = ycur + dt * fv; }
        else              { float yn = yacc + w06 * fv; ycur = yn; ytmp = yn; }
      }
      zA[tm * ZS + td] = f2bf(ytmp);
      f_s[tm][td] = 0.f;
      if (t < 16) {
        if (it > 0) {
          int sp = (it - 1) & 3;
          float lv = l_row[t];
          if (sp == 0)      ldacc[t] = w06 * lv;
          else if (sp < 3)  ldacc[t] += w13 * lv;
          else              ld_row[t] += ldacc[t] + w06 * lv;
        }
        l_row[t] = 0.f;
        zA[t * ZS + 80] = f2bf(te);
      }
      if (it == 0) { ISSUE_STAGE(W2f8, 0, 0); ISSUE_STAGE(W2f8, 1, 1); }
      PHASE_BARRIER();

      // ---- P1: GEMM1 (bf16): h1 = tanh(z @ W1 + b1); store h1 i8 and v i8 ----
      {
        f32x4 a0 = {0,0,0,0}, a1 = {0,0,0,0};
        const unsigned short* ap = zA + lane15 * ZS + q8;
        const unsigned short* wp = W1f + (size_t)(ws32 + lane15) * 96 + q8;
        #pragma unroll
        for (int k0 = 0; k0 < 96; k0 += 32) {
          short8 a = *(const short8*)(ap + k0);
          a0 = MFMA_B16(a, *(const short8*)(wp + k0),           a0);
          a1 = MFMA_B16(a, *(const short8*)(wp + 16 * 96 + k0), a1);
        }
        #pragma unroll
        for (int tl = 0; tl < 2; ++tl) {
          int n = ws32 + tl * 16 + lane15;
          float bias = b1b[n];
          f32x4 ac = tl ? a1 : a0;
          #pragma unroll
          for (int rg = 0; rg < 4; ++rg) {
            float th = fast_tanh(ac[rg] + bias);
            int off = (rowb + rg) * H8 + n;
            h1A8[off] = (char)__float2int_rn(th * 127.f);
            float v = (1.f - th * th) * ur[tl * 4 + rg];
            vA8[off] = (char)__float2int_rn(v * qsv[rg]);
          }
        }
      }
      PHASE_BARRIER();

      // ---- P2: staged dual i8 GEMM, delayed-issue ring (no order-pinning) ----
      {
        int4v ha0 = {0,0,0,0}, ha1 = {0,0,0,0}, wa0 = {0,0,0,0}, wa1 = {0,0,0,0};
        const char* aph = h1A8 + lane15 * H8;
        const char* apv = vA8 + lane15 * H8;
        #pragma unroll
        for (int ks = 0; ks < 8; ++ks) {
          // wait panel ks landed: newest pair in flight is p_{ks+1}; at ks=7 drain all
          if (ks < 7) asm volatile("s_waitcnt vmcnt(2)" ::: "memory");
          else        asm volatile("s_waitcnt vmcnt(0)" ::: "memory");
          const char* bq = &Bst[ks % 3][wave << 11];
          int4v ah = *(const int4v*)(aph + ks * 64 + q16);
          int4v av = *(const int4v*)(apv + ks * 64 + q16);
          int4v b0 = *(const int4v*)(bq + lane15 * 64 + kk2b);
          int4v b1 = *(const int4v*)(bq + (16 + lane15) * 64 + kk2b);
          if (ks < 6) {
            // WAR guard: slot (ks+2)%3 == (ks-1)%3 was read LAST iteration; DS retires
            // in-order, so lgkmcnt(4) (this iteration's 4 reads may remain) suffices.
            asm volatile("s_waitcnt lgkmcnt(4)" ::: "memory");
            ISSUE_STAGE(W2f8, ks + 2, (ks + 2) % 3);
          }
          ha0 = MFMA_I8(ah, b0, ha0);
          ha1 = MFMA_I8(ah, b1, ha1);
          wa0 = MFMA_I8(av, b0, wa0);
          wa1 = MFMA_I8(av, b1, wa1);
        }
        float p0 = 0.f, p1 = 0.f, p2 = 0.f, p3 = 0.f;
        #pragma unroll
        for (int tl = 0; tl < 2; ++tl) {
          int n = ws32 + tl * 16 + lane15;
          float bias = b2b[n];
          float dq = scf[n] * INV2;
          float dqw = scf[n];
          int4v hac = tl ? ha1 : ha0;
          int4v wac = tl ? wa1 : wa0;
          #pragma unroll
          for (int rg = 0; rg < 4; ++rg) {
            float h = fast_tanh((float)hac[rg] * dq + bias);
            h2A[(rowb + rg) * HS + n] = f2bf(h);
            float g2 = e3r[tl * 4 + rg] * (1.f - h * h);
            float w = (float)wac[rg] * dqw * su_[rg];
            float pc = g2 * w;
            if (rg == 0) p0 += pc; else if (rg == 1) p1 += pc;
            else if (rg == 2) p2 += pc; else p3 += pc;
          }
        }
        #pragma unroll
        for (int o = 1; o < 16; o <<= 1) {
          p0 += __shfl_xor(p0, o); p1 += __shfl_xor(p1, o);
          p2 += __shfl_xor(p2, o); p3 += __shfl_xor(p3, o);
        }
        if (lane15 == 0) {
          atomicAdd(&l_row[rowb + 0], p0); atomicAdd(&l_row[rowb + 1], p1);
          atomicAdd(&l_row[rowb + 2], p2); atomicAdd(&l_row[rowb + 3], p3);
        }
      }
      PHASE_BARRIER();

      // ---- P3: prefetch next-eval panels 0,1; GEMM3f (bf16): f += h2 @ W3f ----
      if (it < 31) { ISSUE_STAGE(W2f8, 0, 0); ISSUE_STAGE(W2f8, 1, 1); }
      {
        f32x4 c0 = {0,0,0,0};
        const unsigned short* ap3 = h2A + lane15 * HS + kb3 + q8;
        const unsigned short* wp3 = W3f + (size_t)(nt3 * 16 + lane15) * 512 + kb3 + q8;
        #pragma unroll
        for (int kk = 0; kk < 128; kk += 32)
          c0 = MFMA_B16(*(const short8*)(ap3 + kk), *(const short8*)(wp3 + kk), c0);
        #pragma unroll
        for (int rg = 0; rg < 4; ++rg)
          atomicAdd(&f_s[rowb + rg][nt3 * 16 + lane15], c0[rg]);
      }
      PHASE_BARRIER();
    }

    // ---- bijector finalize: last RK4 stage (s=3) + logdet stage ----
    {
      float fv = f_s[tm][td] + b3b[td];
      float yn = yacc + w06 * fv;
      ycur = yn; ytmp = yn;
    }
    if (t < 16) { ld_row[t] += ldacc[t] + w06 * l_row[t]; l_row[t] = 0.f; }
    __syncthreads();
  }

  out[(size_t)(row0 + tm) * 65 + td] = ycur;
  if (t < 16) out[(size_t)(row0 + t) * 65 + 64] = ld_row[t];
}

extern "C" void kernel_launch(void* const* d_in, const int* in_sizes, int n_in,
                              void* d_out, int out_size, void* d_ws, size_t ws_size,
                              hipStream_t stream) {
  (void)in_sizes; (void)n_in; (void)out_size; (void)ws_size;
  const float* x    = (const float*)d_in[0];
  const float* cond = (const float*)d_in[1];
  const float* eps  = (const float*)d_in[2];
  const float* W1   = (const float*)d_in[3];
  const float* b1   = (const float*)d_in[4];
  const float* W2   = (const float*)d_in[5];
  const float* b2   = (const float*)d_in[6];
  const float* W3   = (const float*)d_in[7];
  const float* b3   = (const float*)d_in[8];
  float* out = (float*)d_out;
  unsigned short* ws = (unsigned short*)d_ws;

  prep_scales<<<4, 256, 0, stream>>>(W2, (float*)((char*)ws + 1114112));
  const int prep_total = 819200;
  prep_bf16<<<(prep_total + 255) / 256, 256, 0, stream>>>(W1, W2, W3, ws);
  ffjord_mfma<<<256, 1024, 0, stream>>>(x, cond, eps, b1, b2, b3, ws, out);
}

// Round 19
// 1035.936 us; speedup vs baseline: 1.9678x; 1.0105x over previous
//
#include <hip/hip_runtime.h>

// FFJORD B=4096 D=64 C=16 H=512, NBIJ=2, NSTEPS=8 RK4 -> 64 sequential MLP+VJP evals.
// Round 25: RESTORE R21 verbatim (session best: 957us dispatch, 2.9x vs baseline).
// A/B record: R20 (__syncthreads, 3-slot delayed ring precursor) 977; R21 (delayed-issue
// ring, no sched_barrier) 957; R22 (own-col f-GEMM, -1 barrier) 1961 REGRESS; R24
// (relaxed lgkmcnt-only barriers) 979 -- barrier-drain hypothesis falsified, revert.
// Structure: i8 W2 forward stream only (416 KB/eval; backward eliminated algebraically
// via u = eps@W1y once/bij, w = v@W2 riding GEMM2's staged panels), 3-deep ring with
// delayed issue (panel ks+2 at ks, WAR = lgkmcnt(4), vmcnt(2) pacing), RK4+logdet
// deferred into next P0, 3 barriers/eval. Ceiling (measured): ~460us fixed +
// 1.27us/KB x 416 KB/eval; remaining restructures all regressed when tested.

typedef __attribute__((ext_vector_type(8))) short short8;
typedef __attribute__((ext_vector_type(4))) float f32x4;
typedef __attribute__((ext_vector_type(4))) int int4v;

#define MFMA_B16(a, b, c) __builtin_amdgcn_mfma_f32_16x16x32_bf16((a), (b), (c), 0, 0, 0)
#define MFMA_I8(a, b, c)  __builtin_amdgcn_mfma_i32_16x16x64_i8((a), (b), (c), 0, 0, 0)

__device__ __forceinline__ unsigned short f2bf(float f) {
  union { float f; unsigned u; } v; v.f = f;
  return (unsigned short)((v.u + 0x7FFFu + ((v.u >> 16) & 1u)) >> 16);
}
__device__ __forceinline__ float bf2f(unsigned short u) {
  union { unsigned u; float f; } v; v.u = ((unsigned)u) << 16; return v.f;
}
__device__ __forceinline__ float fast_tanh(float x) {
  float e = __expf(2.f * x);
  return 1.f - 2.f * __builtin_amdgcn_rcpf(e + 1.f);
}

// ws layout:
// W1f  bf16 [2][512][96]       @ ush 0       (k>=81 zero-padded)
// W2f8 i8   [2][8p][512n][64k] @ byte 196608 (W2^T tiles; byte kk stores
//                                             k = p*64 + (kk ^ ((n>>1&3)<<4)))
// W3f  bf16 [2][64][512]       @ ush 360448  (W3^T: B for f = h2 @ W3)
// W3b  bf16 [2][512][64]       @ ush 425984  (plain W3: B for e3 = eps @ W3^T)
// W1u  bf16 [2][512][64]       @ ush 491520  (W1u[h][d] = W1[d][h]: B for u = eps @ W1y)
// sc   f32  [2][512]           @ byte 1114112 (colmax_n |W2[:,n]|)

__global__ void prep_scales(const float* __restrict__ W2, float* __restrict__ sc) {
  int idx = blockIdx.x * 256 + threadIdx.x;
  if (idx >= 1024) return;
  int ib = idx >> 9, n = idx & 511;
  const float* W = W2 + (size_t)ib * 262144;
  float m = 0.f;
  for (int k = 0; k < 512; ++k) m = fmaxf(m, fabsf(W[(size_t)k * 512 + n]));
  sc[idx] = fmaxf(m, 1e-8f);
}

__global__ void prep_bf16(const float* __restrict__ W1, const float* __restrict__ W2,
                          const float* __restrict__ W3, unsigned short* __restrict__ ws) {
  int o = blockIdx.x * 256 + threadIdx.x;
  char* ws8 = (char*)ws;
  const float* sc = (const float*)(ws8 + 1114112);
  if (o < 98304) {
    int ib = o / 49152, r = o % 49152, n = r / 96, k = r % 96;
    ws[o] = (k < 81) ? f2bf(W1[(size_t)ib * 41472 + k * 512 + n]) : (unsigned short)0;
  } else if (o < 622592) {
    int b = o - 98304;
    int ib = b / 262144, b2 = b % 262144;
    int p = b2 / 32768, r2 = b2 % 32768, n = r2 / 64, kk = r2 & 63;
    int k = p * 64 + (kk ^ (((n >> 1) & 3) << 4));
    float w = W2[(size_t)ib * 262144 + (size_t)k * 512 + n];
    float s = sc[ib * 512 + n];
    int q = (int)rintf(w * (127.f / s));
    q = q > 127 ? 127 : (q < -127 ? -127 : q);
    ws8[196608 + b] = (char)q;
  } else if (o < 688128) {
    int o2 = o - 622592;
    int ib = o2 / 32768, r = o2 % 32768, n = r / 512, k = r % 512;
    ws[360448 + o2] = f2bf(W3[(size_t)ib * 32768 + k * 64 + n]);
  } else if (o < 753664) {
    int o2 = o - 688128;
    ws[425984 + o2] = f2bf(W3[o2]);
  } else if (o < 819200) {
    int o2 = o - 753664;
    int ib = o2 / 32768, r = o2 % 32768, h = r / 64, d = r % 64;
    ws[491520 + o2] = f2bf(W1[(size_t)ib * 41472 + d * 512 + h]);
  }
}

#define ZS 104    // z A-buffer stride, ush (K=96 used; also hosts eps for e3/u GEMMs)
#define HS 520    // bf16 h2 buffer stride, ush
#define H8 528    // i8 h1/v buffer stride, bytes
#define INV2 (1.f / 16129.f)   // 1/(127*127)

// Per-wave async stage of one 2KB slice (own 32 rows x 64 bytes) of a 32KB i8 panel.
#define ISSUE_STAGE(WP, KS, BUF) do {                                                   \
    const char* _s = (WP) + (KS) * 32768 + (wave << 11) + (lane << 4);                  \
    char* _d = &Bst[(BUF)][wave << 11];                                                 \
    __builtin_amdgcn_global_load_lds(                                                   \
        (const __attribute__((address_space(1))) void*)_s,                              \
        (__attribute__((address_space(3))) void*)_d, 16, 0, 0);                         \
    __builtin_amdgcn_global_load_lds(                                                   \
        (const __attribute__((address_space(1))) void*)(_s + 1024),                     \
        (__attribute__((address_space(3))) void*)(_d + 1024), 16, 0, 0);                \
  } while (0)

__global__ __launch_bounds__(1024) void ffjord_mfma(
    const float* __restrict__ x, const float* __restrict__ cond, const float* __restrict__ eps,
    const float* __restrict__ b1g, const float* __restrict__ b2g, const float* __restrict__ b3g,
    const unsigned short* __restrict__ ws, float* __restrict__ out) {
  __shared__ unsigned short zA[16 * ZS];
  __shared__ __align__(16) char h1A8[16 * H8];   // h1 as i8 (q = round(h1*127))
  __shared__ __align__(16) char vA8[16 * H8];    // v = (1-h1^2)*u as i8 (scale su[m])
  __shared__ unsigned short h2A[16 * HS];        // h2 bf16 (GEMM3f A-operand)
  __shared__ __align__(16) char Bst[3][32768];   // staging ring: 3 x 32KB i8 panels
  __shared__ float f_s[16][64];
  __shared__ float l_row[16], ld_row[16], ldacc[16];
  __shared__ int sgu[16];                        // per-bijector rowmax |u| bits

  const int t = threadIdx.x;
  const int wave = t >> 6;
  const int lane = t & 63;
  const int lane15 = lane & 15;
  const int q8 = (lane >> 4) * 8;        // bf16 frag k-offset
  const int q16 = (lane >> 4) * 16;      // i8 frag k-offset (bytes)
  const int rowb = q8 >> 1;              // C/D row base
  const int row0 = blockIdx.x * 16;
  const int ws32 = wave * 32;            // N-slice base for N=512 GEMMs
  const int nt3 = wave & 3;              // N-tile for GEMM3f
  const int kb3 = (wave >> 2) * 128;     // K-slice base for GEMM3f
  const int tm = t >> 6, td = t & 63;    // (row, dim) element owned by this thread

  // swizzled 16B-granule read offset (same XOR for rows lane15 and 16+lane15)
  const int kk2b = q16 ^ (((lane15 >> 1) & 3) << 4);

  // RK4 state in registers (thread-private)
  float ycur, ytmp, yacc = 0.f;
  {
    float xv = x[(size_t)(row0 + tm) * 64 + td];
    ycur = xv; ytmp = xv;
  }
  if (t < 512) {
    int m = t >> 5, kk = t & 31;
    zA[m * ZS + 64 + kk] = (kk < 16) ? f2bf(cond[(size_t)(row0 + m) * 16 + kk]) : (unsigned short)0;
  }
  if (t < 16) { ld_row[t] = 0.f; l_row[t] = 0.f; }

  const float dt = 0.125f;
  const float w06 = dt / 6.f, w13 = dt / 3.f;
  const char* wsb = (const char*)ws;

  for (int ib = 0; ib < 2; ++ib) {
    const unsigned short* W1f = ws + ib * 49152;
    const char* W2f8 = wsb + 196608 + ib * 262144;
    const unsigned short* W3f = ws + 360448 + ib * 32768;
    const unsigned short* W3b = ws + 425984 + ib * 32768;
    const unsigned short* W1u = ws + 491520 + ib * 32768;
    const float* scf = (const float*)(wsb + 1114112) + ib * 512;
    const float* b1b = b1g + ib * 512;
    const float* b2b = b2g + ib * 512;
    const float* b3b = b3g + ib * 64;

    // ---- bijector prologue: stage eps (bf16, borrow zA), e3 + u GEMMs ----
    zA[tm * ZS + td] = f2bf(eps[((size_t)ib * 4096 + row0 + tm) * 64 + td]);
    if (t < 16) sgu[t] = 0;
    __syncthreads();

    float e3r[8], ur[8];
    {
      f32x4 a0 = {0,0,0,0}, a1 = {0,0,0,0};   // e3 = eps @ W3^T
      f32x4 u0 = {0,0,0,0}, u1 = {0,0,0,0};   // u  = eps @ W1y
      const unsigned short* ap = zA + lane15 * ZS + q8;
      const unsigned short* wp3 = W3b + (size_t)(ws32 + lane15) * 64 + q8;
      const unsigned short* wpu = W1u + (size_t)(ws32 + lane15) * 64 + q8;
      #pragma unroll
      for (int kk = 0; kk < 64; kk += 32) {
        short8 a = *(const short8*)(ap + kk);
        a0 = MFMA_B16(a, *(const short8*)(wp3 + kk),           a0);
        a1 = MFMA_B16(a, *(const short8*)(wp3 + 16 * 64 + kk), a1);
        u0 = MFMA_B16(a, *(const short8*)(wpu + kk),           u0);
        u1 = MFMA_B16(a, *(const short8*)(wpu + 16 * 64 + kk), u1);
      }
      #pragma unroll
      for (int rg = 0; rg < 4; ++rg) {
        e3r[rg] = a0[rg]; e3r[4 + rg] = a1[rg];
        ur[rg] = u0[rg];  ur[4 + rg] = u1[rg];
      }
      // per-row max|u| (exact per-bijector bound for the v quantization)
      #pragma unroll
      for (int rg = 0; rg < 4; ++rg) {
        float mr = fmaxf(fabsf(ur[rg]), fabsf(ur[4 + rg]));
        #pragma unroll
        for (int o = 1; o < 16; o <<= 1) mr = fmaxf(mr, __shfl_xor(mr, o));
        if (lane15 == 0) atomicMax(&sgu[rowb + rg], __float_as_int(mr));
      }
    }
    __syncthreads();   // sgu complete; zA about to be rewritten by P0

    float su_[4], qsv[4];
    #pragma unroll
    for (int rg = 0; rg < 4; ++rg) {
      float sg = fmaxf(__int_as_float(sgu[rowb + rg]), 1e-20f);
      su_[rg] = sg * INV2;       // folded w-dequant factor (x scf[n] later)
      qsv[rg] = 127.f / sg;
    }

    for (int it = 0; it < 32; ++it) {
      const int s = it & 3;
      const float te = (it >> 2) * dt + ((s == 0) ? 0.f : (s == 3) ? dt : 0.5f * dt);

      // ---- P0: deferred RK4 + logdet, z build, zero f_s; it==0: prefetch 2 panels ----
      if (it > 0) {
        int sp = (it - 1) & 3;
        float fv = f_s[tm][td] + b3b[td];
        if (sp == 0)      { yacc = ycur + w06 * fv; ytmp = ycur + 0.5f * dt * fv; }
        else if (sp == 1) { yacc += w13 * fv;       ytmp = ycur + 0.5f * dt * fv; }
        else if (sp == 2) { yacc += w13 * fv;       ytmp = ycur + dt * fv; }
        else              { float yn = yacc + w06 * fv; ycur = yn; ytmp = yn; }
      }
      zA[tm * ZS + td] = f2bf(ytmp);
      f_s[tm][td] = 0.f;
      if (t < 16) {
        if (it > 0) {
          int sp = (it - 1) & 3;
          float lv = l_row[t];
          if (sp == 0)      ldacc[t] = w06 * lv;
          else if (sp < 3)  ldacc[t] += w13 * lv;
          else              ld_row[t] += ldacc[t] + w06 * lv;
        }
        l_row[t] = 0.f;
        zA[t * ZS + 80] = f2bf(te);
      }
      if (it == 0) { ISSUE_STAGE(W2f8, 0, 0); ISSUE_STAGE(W2f8, 1, 1); }
      __syncthreads();

      // ---- P1: GEMM1 (bf16): h1 = tanh(z @ W1 + b1); store h1 i8 and v i8 ----
      {
        f32x4 a0 = {0,0,0,0}, a1 = {0,0,0,0};
        const unsigned short* ap = zA + lane15 * ZS + q8;
        const unsigned short* wp = W1f + (size_t)(ws32 + lane15) * 96 + q8;
        #pragma unroll
        for (int k0 = 0; k0 < 96; k0 += 32) {
          short8 a = *(const short8*)(ap + k0);
          a0 = MFMA_B16(a, *(const short8*)(wp + k0),           a0);
          a1 = MFMA_B16(a, *(const short8*)(wp + 16 * 96 + k0), a1);
        }
        #pragma unroll
        for (int tl = 0; tl < 2; ++tl) {
          int n = ws32 + tl * 16 + lane15;
          float bias = b1b[n];
          f32x4 ac = tl ? a1 : a0;
          #pragma unroll
          for (int rg = 0; rg < 4; ++rg) {
            float th = fast_tanh(ac[rg] + bias);
            int off = (rowb + rg) * H8 + n;
            h1A8[off] = (char)__float2int_rn(th * 127.f);
            float v = (1.f - th * th) * ur[tl * 4 + rg];
            vA8[off] = (char)__float2int_rn(v * qsv[rg]);
          }
        }
      }
      __syncthreads();

      // ---- P2: staged dual i8 GEMM, delayed-issue ring (no order-pinning) ----
      {
        int4v ha0 = {0,0,0,0}, ha1 = {0,0,0,0}, wa0 = {0,0,0,0}, wa1 = {0,0,0,0};
        const char* aph = h1A8 + lane15 * H8;
        const char* apv = vA8 + lane15 * H8;
        #pragma unroll
        for (int ks = 0; ks < 8; ++ks) {
          // wait panel ks landed: newest pair in flight is p_{ks+1}; at ks=7 drain all
          if (ks < 7) asm volatile("s_waitcnt vmcnt(2)" ::: "memory");
          else        asm volatile("s_waitcnt vmcnt(0)" ::: "memory");
          const char* bq = &Bst[ks % 3][wave << 11];
          int4v ah = *(const int4v*)(aph + ks * 64 + q16);
          int4v av = *(const int4v*)(apv + ks * 64 + q16);
          int4v b0 = *(const int4v*)(bq + lane15 * 64 + kk2b);
          int4v b1 = *(const int4v*)(bq + (16 + lane15) * 64 + kk2b);
          if (ks < 6) {
            // WAR guard: slot (ks+2)%3 == (ks-1)%3 was read LAST iteration; DS retires
            // in-order, so lgkmcnt(4) (this iteration's 4 reads may remain) suffices.
            asm volatile("s_waitcnt lgkmcnt(4)" ::: "memory");
            ISSUE_STAGE(W2f8, ks + 2, (ks + 2) % 3);
          }
          ha0 = MFMA_I8(ah, b0, ha0);
          ha1 = MFMA_I8(ah, b1, ha1);
          wa0 = MFMA_I8(av, b0, wa0);
          wa1 = MFMA_I8(av, b1, wa1);
        }
        float p0 = 0.f, p1 = 0.f, p2 = 0.f, p3 = 0.f;
        #pragma unroll
        for (int tl = 0; tl < 2; ++tl) {
          int n = ws32 + tl * 16 + lane15;
          float bias = b2b[n];
          float dq = scf[n] * INV2;
          float dqw = scf[n];
          int4v hac = tl ? ha1 : ha0;
          int4v wac = tl ? wa1 : wa0;
          #pragma unroll
          for (int rg = 0; rg < 4; ++rg) {
            float h = fast_tanh((float)hac[rg] * dq + bias);
            h2A[(rowb + rg) * HS + n] = f2bf(h);
            float g2 = e3r[tl * 4 + rg] * (1.f - h * h);
            float w = (float)wac[rg] * dqw * su_[rg];
            float pc = g2 * w;
            if (rg == 0) p0 += pc; else if (rg == 1) p1 += pc;
            else if (rg == 2) p2 += pc; else p3 += pc;
          }
        }
        #pragma unroll
        for (int o = 1; o < 16; o <<= 1) {
          p0 += __shfl_xor(p0, o); p1 += __shfl_xor(p1, o);
          p2 += __shfl_xor(p2, o); p3 += __shfl_xor(p3, o);
        }
        if (lane15 == 0) {
          atomicAdd(&l_row[rowb + 0], p0); atomicAdd(&l_row[rowb + 1], p1);
          atomicAdd(&l_row[rowb + 2], p2); atomicAdd(&l_row[rowb + 3], p3);
        }
      }
      __syncthreads();

      // ---- P3: prefetch next-eval panels 0,1; GEMM3f (bf16): f += h2 @ W3f ----
      if (it < 31) { ISSUE_STAGE(W2f8, 0, 0); ISSUE_STAGE(W2f8, 1, 1); }
      {
        f32x4 c0 = {0,0,0,0};
        const unsigned short* ap3 = h2A + lane15 * HS + kb3 + q8;
        const unsigned short* wp3 = W3f + (size_t)(nt3 * 16 + lane15) * 512 + kb3 + q8;
        #pragma unroll
        for (int kk = 0; kk < 128; kk += 32)
          c0 = MFMA_B16(*(const short8*)(ap3 + kk), *(const short8*)(wp3 + kk), c0);
        #pragma unroll
        for (int rg = 0; rg < 4; ++rg)
          atomicAdd(&f_s[rowb + rg][nt3 * 16 + lane15], c0[rg]);
      }
      __syncthreads();
    }

    // ---- bijector finalize: last RK4 stage (s=3) + logdet stage ----
    {
      float fv = f_s[tm][td] + b3b[td];
      float yn = yacc + w06 * fv;
      ycur = yn; ytmp = yn;
    }
    if (t < 16) { ld_row[t] += ldacc[t] + w06 * l_row[t]; l_row[t] = 0.f; }
    __syncthreads();
  }

  out[(size_t)(row0 + tm) * 65 + td] = ycur;
  if (t < 16) out[(size_t)(row0 + t) * 65 + 64] = ld_row[t];
}

extern "C" void kernel_launch(void* const* d_in, const int* in_sizes, int n_in,
                              void* d_out, int out_size, void* d_ws, size_t ws_size,
                              hipStream_t stream) {
  (void)in_sizes; (void)n_in; (void)out_size; (void)ws_size;
  const float* x    = (const float*)d_in[0];
  const float* cond = (const float*)d_in[1];
  const float* eps  = (const float*)d_in[2];
  const float* W1   = (const float*)d_in[3];
  const float* b1   = (const float*)d_in[4];
  const float* W2   = (const float*)d_in[5];
  const float* b2   = (const float*)d_in[6];
  const float* W3   = (const float*)d_in[7];
  const float* b3   = (const float*)d_in[8];
  float* out = (float*)d_out;
  unsigned short* ws = (unsigned short*)d_ws;

  prep_scales<<<4, 256, 0, stream>>>(W2, (float*)((char*)ws + 1114112));
  const int prep_total = 819200;
  prep_bf16<<<(prep_total + 255) / 256, 256, 0, stream>>>(W1, W2, W3, ws);
  ffjord_mfma<<<256, 1024, 0, stream>>>(x, cond, eps, b1, b2, b3, ws, out);
}

// Round 20
// 962.584 us; speedup vs baseline: 2.1177x; 1.0762x over previous
//
#include <hip/hip_runtime.h>

// FFJORD B=4096 D=64 C=16 H=512, NBIJ=2, NSTEPS=8 RK4 -> 64 sequential MLP+VJP evals.
// Round 26: main kernel = R21/R25 verbatim (triple-confirmed local optimum, ~950us
// dispatch). This round attacks the OTHER ~85us of the scored bench number: prep.
// Old prep_scales = 1024 threads x 512-iter serial stride-2KB loops (~45us on 4 CUs);
// old prep_bf16 W2 branch = 1 uncoalesced stride-2KB read per output byte. New:
// (1) prep_sc_init + prep_scales: 64 blocks, coalesced row reads, atomicMax on
//     float-bits (non-negative floats compare as ints; floor applied at pack time);
// (2) prep_w2: LDS-tiled 64x64 transpose -> swizzle+quantize -> coalesced 16B stores,
//     bit-identical output to the old formula;
// (3) prep_rest: the remaining small bf16 copies (W1f/W3f/W3b/W1u), unchanged form.

typedef __attribute__((ext_vector_type(8))) short short8;
typedef __attribute__((ext_vector_type(4))) float f32x4;
typedef __attribute__((ext_vector_type(4))) int int4v;

#define MFMA_B16(a, b, c) __builtin_amdgcn_mfma_f32_16x16x32_bf16((a), (b), (c), 0, 0, 0)
#define MFMA_I8(a, b, c)  __builtin_amdgcn_mfma_i32_16x16x64_i8((a), (b), (c), 0, 0, 0)

__device__ __forceinline__ unsigned short f2bf(float f) {
  union { float f; unsigned u; } v; v.f = f;
  return (unsigned short)((v.u + 0x7FFFu + ((v.u >> 16) & 1u)) >> 16);
}
__device__ __forceinline__ float bf2f(unsigned short u) {
  union { unsigned u; float f; } v; v.u = ((unsigned)u) << 16; return v.f;
}
__device__ __forceinline__ float fast_tanh(float x) {
  float e = __expf(2.f * x);
  return 1.f - 2.f * __builtin_amdgcn_rcpf(e + 1.f);
}

// ws layout:
// W1f  bf16 [2][512][96]       @ ush 0       (k>=81 zero-padded)
// W2f8 i8   [2][8p][512n][64k] @ byte 196608 (W2^T tiles; byte kk stores
//                                             k = p*64 + (kk ^ ((n>>1&3)<<4)))
// W3f  bf16 [2][64][512]       @ ush 360448  (W3^T: B for f = h2 @ W3)
// W3b  bf16 [2][512][64]       @ ush 425984  (plain W3: B for e3 = eps @ W3^T)
// W1u  bf16 [2][512][64]       @ ush 491520  (W1u[h][d] = W1[d][h]: B for u = eps @ W1y)
// sc   f32  [2][512]           @ byte 1114112 (colmax_n |W2[:,n]| as float bits)

__global__ void prep_sc_init(float* __restrict__ sc) {
  int i = blockIdx.x * 256 + threadIdx.x;
  if (i < 1024) ((int*)sc)[i] = 0;
}

// 64 blocks x 256 threads: block b -> ib = b>>5, row-block = b&31 (16 rows of 512).
// Coalesced row reads; column max via global atomicMax on non-negative float bits.
__global__ void prep_scales(const float* __restrict__ W2, float* __restrict__ sc) {
  int ib = blockIdx.x >> 5, rb = blockIdx.x & 31;
  const float* W = W2 + (size_t)ib * 262144 + (size_t)rb * 16 * 512;
  int c = threadIdx.x;
  float m0 = 0.f, m1 = 0.f;
  #pragma unroll 4
  for (int r = 0; r < 16; ++r) {
    m0 = fmaxf(m0, fabsf(W[r * 512 + c]));
    m1 = fmaxf(m1, fabsf(W[r * 512 + c + 256]));
  }
  atomicMax((int*)sc + ib * 512 + c,       __float_as_int(m0));
  atomicMax((int*)sc + ib * 512 + c + 256, __float_as_int(m1));
}

// 128 blocks (2 ib x 8 p x 8 nb) x 256 threads: LDS-tiled transpose + quantize.
// Output is bit-identical to the old per-byte formula.
__global__ void prep_w2(const float* __restrict__ W2, unsigned short* __restrict__ ws) {
  __shared__ float tile[64][65];   // [k_local][n_local], padded
  __shared__ float scl[64];
  const int t = threadIdx.x;
  const int blk = blockIdx.x;
  const int ib = blk >> 6, p = (blk >> 3) & 7, nb = blk & 7;
  const float* W = W2 + (size_t)ib * 262144 + (size_t)(p * 64) * 512 + nb * 64;
  const int* scI = (const int*)((const char*)ws + 1114112) + ib * 512 + nb * 64;

  #pragma unroll
  for (int pass = 0; pass < 16; ++pass) {
    int k = (t >> 6) + pass * 4, n = t & 63;
    tile[k][n] = W[(size_t)k * 512 + n];
  }
  if (t < 64) scl[t] = fmaxf(__int_as_float(scI[t]), 1e-8f);
  __syncthreads();

  char* out = (char*)ws + 196608 + (size_t)ib * 262144 + (size_t)p * 32768
            + (size_t)nb * 64 * 64;
  const int nl = t >> 2, kk0 = (t & 3) * 16;
  const int n = nb * 64 + nl;
  const int sw = ((n >> 1) & 3) << 4;
  const float inv = 127.f / scl[nl];
  int words[4];
  #pragma unroll
  for (int w4 = 0; w4 < 4; ++w4) {
    int v = 0;
    #pragma unroll
    for (int j = 0; j < 4; ++j) {
      int kk = kk0 + w4 * 4 + j;
      int kloc = kk ^ sw;
      int q = (int)rintf(tile[kloc][nl] * inv);
      q = q > 127 ? 127 : (q < -127 ? -127 : q);
      v |= (q & 0xff) << (8 * j);
    }
    words[w4] = v;
  }
  int4v o4 = {words[0], words[1], words[2], words[3]};
  *(int4v*)(out + (size_t)nl * 64 + kk0) = o4;
}

// Remaining bf16 regions (W1f / W3f / W3b / W1u): 294912 elements.
__global__ void prep_rest(const float* __restrict__ W1, const float* __restrict__ W3,
                          unsigned short* __restrict__ ws) {
  int o = blockIdx.x * 256 + threadIdx.x;
  if (o < 98304) {
    int ib = o / 49152, r = o % 49152, n = r / 96, k = r % 96;
    ws[o] = (k < 81) ? f2bf(W1[(size_t)ib * 41472 + k * 512 + n]) : (unsigned short)0;
  } else if (o < 163840) {
    int o2 = o - 98304;
    int ib = o2 >> 15, r = o2 & 32767, n = r / 512, k = r % 512;
    ws[360448 + o2] = f2bf(W3[(size_t)ib * 32768 + k * 64 + n]);
  } else if (o < 229376) {
    int o2 = o - 163840;
    ws[425984 + o2] = f2bf(W3[o2]);
  } else if (o < 294912) {
    int o2 = o - 229376;
    int ib = o2 >> 15, r = o2 & 32767, h = r / 64, d = r & 63;
    ws[491520 + o2] = f2bf(W1[(size_t)ib * 41472 + (size_t)d * 512 + h]);
  }
}

#define ZS 104    // z A-buffer stride, ush (K=96 used; also hosts eps for e3/u GEMMs)
#define HS 520    // bf16 h2 buffer stride, ush
#define H8 528    // i8 h1/v buffer stride, bytes
#define INV2 (1.f / 16129.f)   // 1/(127*127)

// Per-wave async stage of one 2KB slice (own 32 rows x 64 bytes) of a 32KB i8 panel.
#define ISSUE_STAGE(WP, KS, BUF) do {                                                   \
    const char* _s = (WP) + (KS) * 32768 + (wave << 11) + (lane << 4);                  \
    char* _d = &Bst[(BUF)][wave << 11];                                                 \
    __builtin_amdgcn_global_load_lds(                                                   \
        (const __attribute__((address_space(1))) void*)_s,                              \
        (__attribute__((address_space(3))) void*)_d, 16, 0, 0);                         \
    __builtin_amdgcn_global_load_lds(                                                   \
        (const __attribute__((address_space(1))) void*)(_s + 1024),                     \
        (__attribute__((address_space(3))) void*)(_d + 1024), 16, 0, 0);                \
  } while (0)

__global__ __launch_bounds__(1024) void ffjord_mfma(
    const float* __restrict__ x, const float* __restrict__ cond, const float* __restrict__ eps,
    const float* __restrict__ b1g, const float* __restrict__ b2g, const float* __restrict__ b3g,
    const unsigned short* __restrict__ ws, float* __restrict__ out) {
  __shared__ unsigned short zA[16 * ZS];
  __shared__ __align__(16) char h1A8[16 * H8];   // h1 as i8 (q = round(h1*127))
  __shared__ __align__(16) char vA8[16 * H8];    // v = (1-h1^2)*u as i8 (scale su[m])
  __shared__ unsigned short h2A[16 * HS];        // h2 bf16 (GEMM3f A-operand)
  __shared__ __align__(16) char Bst[3][32768];   // staging ring: 3 x 32KB i8 panels
  __shared__ float f_s[16][64];
  __shared__ float l_row[16], ld_row[16], ldacc[16];
  __shared__ int sgu[16];                        // per-bijector rowmax |u| bits

  const int t = threadIdx.x;
  const int wave = t >> 6;
  const int lane = t & 63;
  const int lane15 = lane & 15;
  const int q8 = (lane >> 4) * 8;        // bf16 frag k-offset
  const int q16 = (lane >> 4) * 16;      // i8 frag k-offset (bytes)
  const int rowb = q8 >> 1;              // C/D row base
  const int row0 = blockIdx.x * 16;
  const int ws32 = wave * 32;            // N-slice base for N=512 GEMMs
  const int nt3 = wave & 3;              // N-tile for GEMM3f
  const int kb3 = (wave >> 2) * 128;     // K-slice base for GEMM3f
  const int tm = t >> 6, td = t & 63;    // (row, dim) element owned by this thread

  // swizzled 16B-granule read offset (same XOR for rows lane15 and 16+lane15)
  const int kk2b = q16 ^ (((lane15 >> 1) & 3) << 4);

  // RK4 state in registers (thread-private)
  float ycur, ytmp, yacc = 0.f;
  {
    float xv = x[(size_t)(row0 + tm) * 64 + td];
    ycur = xv; ytmp = xv;
  }
  if (t < 512) {
    int m = t >> 5, kk = t & 31;
    zA[m * ZS + 64 + kk] = (kk < 16) ? f2bf(cond[(size_t)(row0 + m) * 16 + kk]) : (unsigned short)0;
  }
  if (t < 16) { ld_row[t] = 0.f; l_row[t] = 0.f; }

  const float dt = 0.125f;
  const float w06 = dt / 6.f, w13 = dt / 3.f;
  const char* wsb = (const char*)ws;

  for (int ib = 0; ib < 2; ++ib) {
    const unsigned short* W1f = ws + ib * 49152;
    const char* W2f8 = wsb + 196608 + ib * 262144;
    const unsigned short* W3f = ws + 360448 + ib * 32768;
    const unsigned short* W3b = ws + 425984 + ib * 32768;
    const unsigned short* W1u = ws + 491520 + ib * 32768;
    const float* scf = (const float*)(wsb + 1114112) + ib * 512;
    const float* b1b = b1g + ib * 512;
    const float* b2b = b2g + ib * 512;
    const float* b3b = b3g + ib * 64;

    // ---- bijector prologue: stage eps (bf16, borrow zA), e3 + u GEMMs ----
    zA[tm * ZS + td] = f2bf(eps[((size_t)ib * 4096 + row0 + tm) * 64 + td]);
    if (t < 16) sgu[t] = 0;
    __syncthreads();

    float e3r[8], ur[8];
    {
      f32x4 a0 = {0,0,0,0}, a1 = {0,0,0,0};   // e3 = eps @ W3^T
      f32x4 u0 = {0,0,0,0}, u1 = {0,0,0,0};   // u  = eps @ W1y
      const unsigned short* ap = zA + lane15 * ZS + q8;
      const unsigned short* wp3 = W3b + (size_t)(ws32 + lane15) * 64 + q8;
      const unsigned short* wpu = W1u + (size_t)(ws32 + lane15) * 64 + q8;
      #pragma unroll
      for (int kk = 0; kk < 64; kk += 32) {
        short8 a = *(const short8*)(ap + kk);
        a0 = MFMA_B16(a, *(const short8*)(wp3 + kk),           a0);
        a1 = MFMA_B16(a, *(const short8*)(wp3 + 16 * 64 + kk), a1);
        u0 = MFMA_B16(a, *(const short8*)(wpu + kk),           u0);
        u1 = MFMA_B16(a, *(const short8*)(wpu + 16 * 64 + kk), u1);
      }
      #pragma unroll
      for (int rg = 0; rg < 4; ++rg) {
        e3r[rg] = a0[rg]; e3r[4 + rg] = a1[rg];
        ur[rg] = u0[rg];  ur[4 + rg] = u1[rg];
      }
      // per-row max|u| (exact per-bijector bound for the v quantization)
      #pragma unroll
      for (int rg = 0; rg < 4; ++rg) {
        float mr = fmaxf(fabsf(ur[rg]), fabsf(ur[4 + rg]));
        #pragma unroll
        for (int o = 1; o < 16; o <<= 1) mr = fmaxf(mr, __shfl_xor(mr, o));
        if (lane15 == 0) atomicMax(&sgu[rowb + rg], __float_as_int(mr));
      }
    }
    __syncthreads();   // sgu complete; zA about to be rewritten by P0

    float su_[4], qsv[4];
    #pragma unroll
    for (int rg = 0; rg < 4; ++rg) {
      float sg = fmaxf(__int_as_float(sgu[rowb + rg]), 1e-20f);
      su_[rg] = sg * INV2;       // folded w-dequant factor (x scf[n] later)
      qsv[rg] = 127.f / sg;
    }

    for (int it = 0; it < 32; ++it) {
      const int s = it & 3;
      const float te = (it >> 2) * dt + ((s == 0) ? 0.f : (s == 3) ? dt : 0.5f * dt);

      // ---- P0: deferred RK4 + logdet, z build, zero f_s; it==0: prefetch 2 panels ----
      if (it > 0) {
        int sp = (it - 1) & 3;
        float fv = f_s[tm][td] + b3b[td];
        if (sp == 0)      { yacc = ycur + w06 * fv; ytmp = ycur + 0.5f * dt * fv; }
        else if (sp == 1) { yacc += w13 * fv;       ytmp = ycur + 0.5f * dt * fv; }
        else if (sp == 2) { yacc += w13 * fv;       ytmp = ycur + dt * fv; }
        else              { float yn = yacc + w06 * fv; ycur = yn; ytmp = yn; }
      }
      zA[tm * ZS + td] = f2bf(ytmp);
      f_s[tm][td] = 0.f;
      if (t < 16) {
        if (it > 0) {
          int sp = (it - 1) & 3;
          float lv = l_row[t];
          if (sp == 0)      ldacc[t] = w06 * lv;
          else if (sp < 3)  ldacc[t] += w13 * lv;
          else              ld_row[t] += ldacc[t] + w06 * lv;
        }
        l_row[t] = 0.f;
        zA[t * ZS + 80] = f2bf(te);
      }
      if (it == 0) { ISSUE_STAGE(W2f8, 0, 0); ISSUE_STAGE(W2f8, 1, 1); }
      __syncthreads();

      // ---- P1: GEMM1 (bf16): h1 = tanh(z @ W1 + b1); store h1 i8 and v i8 ----
      {
        f32x4 a0 = {0,0,0,0}, a1 = {0,0,0,0};
        const unsigned short* ap = zA + lane15 * ZS + q8;
        const unsigned short* wp = W1f + (size_t)(ws32 + lane15) * 96 + q8;
        #pragma unroll
        for (int k0 = 0; k0 < 96; k0 += 32) {
          short8 a = *(const short8*)(ap + k0);
          a0 = MFMA_B16(a, *(const short8*)(wp + k0),           a0);
          a1 = MFMA_B16(a, *(const short8*)(wp + 16 * 96 + k0), a1);
        }
        #pragma unroll
        for (int tl = 0; tl < 2; ++tl) {
          int n = ws32 + tl * 16 + lane15;
          float bias = b1b[n];
          f32x4 ac = tl ? a1 : a0;
          #pragma unroll
          for (int rg = 0; rg < 4; ++rg) {
            float th = fast_tanh(ac[rg] + bias);
            int off = (rowb + rg) * H8 + n;
            h1A8[off] = (char)__float2int_rn(th * 127.f);
            float v = (1.f - th * th) * ur[tl * 4 + rg];
            vA8[off] = (char)__float2int_rn(v * qsv[rg]);
          }
        }
      }
      __syncthreads();

      // ---- P2: staged dual i8 GEMM, delayed-issue ring (no order-pinning) ----
      {
        int4v ha0 = {0,0,0,0}, ha1 = {0,0,0,0}, wa0 = {0,0,0,0}, wa1 = {0,0,0,0};
        const char* aph = h1A8 + lane15 * H8;
        const char* apv = vA8 + lane15 * H8;
        #pragma unroll
        for (int ks = 0; ks < 8; ++ks) {
          // wait panel ks landed: newest pair in flight is p_{ks+1}; at ks=7 drain all
          if (ks < 7) asm volatile("s_waitcnt vmcnt(2)" ::: "memory");
          else        asm volatile("s_waitcnt vmcnt(0)" ::: "memory");
          const char* bq = &Bst[ks % 3][wave << 11];
          int4v ah = *(const int4v*)(aph + ks * 64 + q16);
          int4v av = *(const int4v*)(apv + ks * 64 + q16);
          int4v b0 = *(const int4v*)(bq + lane15 * 64 + kk2b);
          int4v b1 = *(const int4v*)(bq + (16 + lane15) * 64 + kk2b);
          if (ks < 6) {
            // WAR guard: slot (ks+2)%3 == (ks-1)%3 was read LAST iteration; DS retires
            // in-order, so lgkmcnt(4) (this iteration's 4 reads may remain) suffices.
            asm volatile("s_waitcnt lgkmcnt(4)" ::: "memory");
            ISSUE_STAGE(W2f8, ks + 2, (ks + 2) % 3);
          }
          ha0 = MFMA_I8(ah, b0, ha0);
          ha1 = MFMA_I8(ah, b1, ha1);
          wa0 = MFMA_I8(av, b0, wa0);
          wa1 = MFMA_I8(av, b1, wa1);
        }
        float p0 = 0.f, p1 = 0.f, p2 = 0.f, p3 = 0.f;
        #pragma unroll
        for (int tl = 0; tl < 2; ++tl) {
          int n = ws32 + tl * 16 + lane15;
          float bias = b2b[n];
          float dq = scf[n] * INV2;
          float dqw = scf[n];
          int4v hac = tl ? ha1 : ha0;
          int4v wac = tl ? wa1 : wa0;
          #pragma unroll
          for (int rg = 0; rg < 4; ++rg) {
            float h = fast_tanh((float)hac[rg] * dq + bias);
            h2A[(rowb + rg) * HS + n] = f2bf(h);
            float g2 = e3r[tl * 4 + rg] * (1.f - h * h);
            float w = (float)wac[rg] * dqw * su_[rg];
            float pc = g2 * w;
            if (rg == 0) p0 += pc; else if (rg == 1) p1 += pc;
            else if (rg == 2) p2 += pc; else p3 += pc;
          }
        }
        #pragma unroll
        for (int o = 1; o < 16; o <<= 1) {
          p0 += __shfl_xor(p0, o); p1 += __shfl_xor(p1, o);
          p2 += __shfl_xor(p2, o); p3 += __shfl_xor(p3, o);
        }
        if (lane15 == 0) {
          atomicAdd(&l_row[rowb + 0], p0); atomicAdd(&l_row[rowb + 1], p1);
          atomicAdd(&l_row[rowb + 2], p2); atomicAdd(&l_row[rowb + 3], p3);
        }
      }
      __syncthreads();

      // ---- P3: prefetch next-eval panels 0,1; GEMM3f (bf16): f += h2 @ W3f ----
      if (it < 31) { ISSUE_STAGE(W2f8, 0, 0); ISSUE_STAGE(W2f8, 1, 1); }
      {
        f32x4 c0 = {0,0,0,0};
        const unsigned short* ap3 = h2A + lane15 * HS + kb3 + q8;
        const unsigned short* wp3 = W3f + (size_t)(nt3 * 16 + lane15) * 512 + kb3 + q8;
        #pragma unroll
        for (int kk = 0; kk < 128; kk += 32)
          c0 = MFMA_B16(*(const short8*)(ap3 + kk), *(const short8*)(wp3 + kk), c0);
        #pragma unroll
        for (int rg = 0; rg < 4; ++rg)
          atomicAdd(&f_s[rowb + rg][nt3 * 16 + lane15], c0[rg]);
      }
      __syncthreads();
    }

    // ---- bijector finalize: last RK4 stage (s=3) + logdet stage ----
    {
      float fv = f_s[tm][td] + b3b[td];
      float yn = yacc + w06 * fv;
      ycur = yn; ytmp = yn;
    }
    if (t < 16) { ld_row[t] += ldacc[t] + w06 * l_row[t]; l_row[t] = 0.f; }
    __syncthreads();
  }

  out[(size_t)(row0 + tm) * 65 + td] = ycur;
  if (t < 16) out[(size_t)(row0 + t) * 65 + 64] = ld_row[t];
}

extern "C" void kernel_launch(void* const* d_in, const int* in_sizes, int n_in,
                              void* d_out, int out_size, void* d_ws, size_t ws_size,
                              hipStream_t stream) {
  (void)in_sizes; (void)n_in; (void)out_size; (void)ws_size;
  const float* x    = (const float*)d_in[0];
  const float* cond = (const float*)d_in[1];
  const float* eps  = (const float*)d_in[2];
  const float* W1   = (const float*)d_in[3];
  const float* b1   = (const float*)d_in[4];
  const float* W2   = (const float*)d_in[5];
  const float* b2   = (const float*)d_in[6];
  const float* W3   = (const float*)d_in[7];
  const float* b3   = (const float*)d_in[8];
  float* out = (float*)d_out;
  unsigned short* ws = (unsigned short*)d_ws;
  float* sc = (float*)((char*)ws + 1114112);

  prep_sc_init<<<4, 256, 0, stream>>>(sc);
  prep_scales<<<64, 256, 0, stream>>>(W2, sc);
  prep_w2<<<128, 256, 0, stream>>>(W2, ws);
  prep_rest<<<1152, 256, 0, stream>>>(W1, W3, ws);
  ffjord_mfma<<<256, 1024, 0, stream>>>(x, cond, eps, b1, b2, b3, ws, out);
}

// Round 21
// 925.538 us; speedup vs baseline: 2.2025x; 1.0400x over previous
//
#include <hip/hip_runtime.h>

// FFJORD B=4096 D=64 C=16 H=512, NBIJ=2, NSTEPS=8 RK4 -> 64 sequential MLP+VJP evals.
// Round 27: main loop = R21/R25 (triple-confirmed optimum) + ONE isolated change:
// cbias-lite. P1's K=96 decomposes: cond part is per-bijector constant -> computed once
// per bijector (single K=32 MFMA pair; B zero-pad kills the t column) into bf16 LDS
// cbias[16][520] (+16.6KB, still 1 blk/CU); t part folded as te*w1t[n] (f32, exact).
// P1 per-eval K drops 96->64: -2 unhidden post-barrier L2 B-loads, -2 MFMA, -1 A-read;
// b1 loads leave the eval loop. Register-neutral by construction (the R18/R19 failure
// was live-state overflow at the hard 64-VGPR allocation; this adds none).
// Prep = R26's coalesced kernels (+W1c/w1t regions).

typedef __attribute__((ext_vector_type(8))) short short8;
typedef __attribute__((ext_vector_type(4))) float f32x4;
typedef __attribute__((ext_vector_type(4))) int int4v;

#define MFMA_B16(a, b, c) __builtin_amdgcn_mfma_f32_16x16x32_bf16((a), (b), (c), 0, 0, 0)
#define MFMA_I8(a, b, c)  __builtin_amdgcn_mfma_i32_16x16x64_i8((a), (b), (c), 0, 0, 0)

__device__ __forceinline__ unsigned short f2bf(float f) {
  union { float f; unsigned u; } v; v.f = f;
  return (unsigned short)((v.u + 0x7FFFu + ((v.u >> 16) & 1u)) >> 16);
}
__device__ __forceinline__ float bf2f(unsigned short u) {
  union { unsigned u; float f; } v; v.u = ((unsigned)u) << 16; return v.f;
}
__device__ __forceinline__ float fast_tanh(float x) {
  float e = __expf(2.f * x);
  return 1.f - 2.f * __builtin_amdgcn_rcpf(e + 1.f);
}

// ws layout:
// W1f  bf16 [2][512][96]       @ ush 0       (rows 0..63 used per eval; k>=81 zero-pad)
// W2f8 i8   [2][8p][512n][64k] @ byte 196608 (W2^T tiles; byte kk stores
//                                             k = p*64 + (kk ^ ((n>>1&3)<<4)))
// W3f  bf16 [2][64][512]       @ ush 360448  (W3^T: B for f = h2 @ W3)
// W3b  bf16 [2][512][64]       @ ush 425984  (plain W3: B for e3 = eps @ W3^T)
// W1u  bf16 [2][512][64]       @ ush 491520  (W1u[h][d] = W1[d][h]: B for u = eps @ W1y)
// sc   f32  [2][512]           @ byte 1114112 (colmax_n |W2[:,n]| as float bits)
// W1c  bf16 [2][512][32]       @ ush 559104  (W1 rows 64..79 as B[n][kk], kk>=16 -> 0)
// w1t  f32  [2][512]           @ f32 312320  (W1 row 80)

__global__ void prep_sc_init(float* __restrict__ sc) {
  int i = blockIdx.x * 256 + threadIdx.x;
  if (i < 1024) ((int*)sc)[i] = 0;
}

__global__ void prep_scales(const float* __restrict__ W2, float* __restrict__ sc) {
  int ib = blockIdx.x >> 5, rb = blockIdx.x & 31;
  const float* W = W2 + (size_t)ib * 262144 + (size_t)rb * 16 * 512;
  int c = threadIdx.x;
  float m0 = 0.f, m1 = 0.f;
  #pragma unroll 4
  for (int r = 0; r < 16; ++r) {
    m0 = fmaxf(m0, fabsf(W[r * 512 + c]));
    m1 = fmaxf(m1, fabsf(W[r * 512 + c + 256]));
  }
  atomicMax((int*)sc + ib * 512 + c,       __float_as_int(m0));
  atomicMax((int*)sc + ib * 512 + c + 256, __float_as_int(m1));
}

__global__ void prep_w2(const float* __restrict__ W2, unsigned short* __restrict__ ws) {
  __shared__ float tile[64][65];
  __shared__ float scl[64];
  const int t = threadIdx.x;
  const int blk = blockIdx.x;
  const int ib = blk >> 6, p = (blk >> 3) & 7, nb = blk & 7;
  const float* W = W2 + (size_t)ib * 262144 + (size_t)(p * 64) * 512 + nb * 64;
  const int* scI = (const int*)((const char*)ws + 1114112) + ib * 512 + nb * 64;

  #pragma unroll
  for (int pass = 0; pass < 16; ++pass) {
    int k = (t >> 6) + pass * 4, n = t & 63;
    tile[k][n] = W[(size_t)k * 512 + n];
  }
  if (t < 64) scl[t] = fmaxf(__int_as_float(scI[t]), 1e-8f);
  __syncthreads();

  char* out = (char*)ws + 196608 + (size_t)ib * 262144 + (size_t)p * 32768
            + (size_t)nb * 64 * 64;
  const int nl = t >> 2, kk0 = (t & 3) * 16;
  const int n = nb * 64 + nl;
  const int sw = ((n >> 1) & 3) << 4;
  const float inv = 127.f / scl[nl];
  int words[4];
  #pragma unroll
  for (int w4 = 0; w4 < 4; ++w4) {
    int v = 0;
    #pragma unroll
    for (int j = 0; j < 4; ++j) {
      int kk = kk0 + w4 * 4 + j;
      int kloc = kk ^ sw;
      int q = (int)rintf(tile[kloc][nl] * inv);
      q = q > 127 ? 127 : (q < -127 ? -127 : q);
      v |= (q & 0xff) << (8 * j);
    }
    words[w4] = v;
  }
  int4v o4 = {words[0], words[1], words[2], words[3]};
  *(int4v*)(out + (size_t)nl * 64 + kk0) = o4;
}

// bf16 regions + W1c + w1t: 294912 + 32768 + 1024 = 328704 items.
__global__ void prep_rest(const float* __restrict__ W1, const float* __restrict__ W3,
                          unsigned short* __restrict__ ws) {
  int o = blockIdx.x * 256 + threadIdx.x;
  if (o < 98304) {
    int ib = o / 49152, r = o % 49152, n = r / 96, k = r % 96;
    ws[o] = (k < 81) ? f2bf(W1[(size_t)ib * 41472 + k * 512 + n]) : (unsigned short)0;
  } else if (o < 163840) {
    int o2 = o - 98304;
    int ib = o2 >> 15, r = o2 & 32767, n = r / 512, k = r % 512;
    ws[360448 + o2] = f2bf(W3[(size_t)ib * 32768 + k * 64 + n]);
  } else if (o < 229376) {
    int o2 = o - 163840;
    ws[425984 + o2] = f2bf(W3[o2]);
  } else if (o < 294912) {
    int o2 = o - 229376;
    int ib = o2 >> 15, r = o2 & 32767, h = r / 64, d = r & 63;
    ws[491520 + o2] = f2bf(W1[(size_t)ib * 41472 + (size_t)d * 512 + h]);
  } else if (o < 327680) {
    int o2 = o - 294912;
    int ib = o2 >> 14, r = o2 & 16383, n = r >> 5, kk = r & 31;
    ws[559104 + o2] = (kk < 16) ? f2bf(W1[(size_t)ib * 41472 + (size_t)(64 + kk) * 512 + n])
                                : (unsigned short)0;
  } else if (o < 328704) {
    int o2 = o - 327680;
    int ib = o2 >> 9, n = o2 & 511;
    ((float*)ws)[312320 + o2] = W1[(size_t)ib * 41472 + 80 * 512 + n];
  }
}

#define ZS 104    // z A-buffer stride, ush (cols 0-63 y/eps; 64-95 cond, persistent)
#define HS 520    // bf16 h2 / cbias buffer stride, ush
#define H8 528    // i8 h1/v buffer stride, bytes
#define INV2 (1.f / 16129.f)   // 1/(127*127)

// Per-wave async stage of one 2KB slice (own 32 rows x 64 bytes) of a 32KB i8 panel.
#define ISSUE_STAGE(WP, KS, BUF) do {                                                   \
    const char* _s = (WP) + (KS) * 32768 + (wave << 11) + (lane << 4);                  \
    char* _d = &Bst[(BUF)][wave << 11];                                                 \
    __builtin_amdgcn_global_load_lds(                                                   \
        (const __attribute__((address_space(1))) void*)_s,                              \
        (__attribute__((address_space(3))) void*)_d, 16, 0, 0);                         \
    __builtin_amdgcn_global_load_lds(                                                   \
        (const __attribute__((address_space(1))) void*)(_s + 1024),                     \
        (__attribute__((address_space(3))) void*)(_d + 1024), 16, 0, 0);                \
  } while (0)

__global__ __launch_bounds__(1024) void ffjord_mfma(
    const float* __restrict__ x, const float* __restrict__ cond, const float* __restrict__ eps,
    const float* __restrict__ b1g, const float* __restrict__ b2g, const float* __restrict__ b3g,
    const unsigned short* __restrict__ ws, float* __restrict__ out) {
  __shared__ unsigned short zA[16 * ZS];
  __shared__ __align__(16) char h1A8[16 * H8];   // h1 as i8 (q = round(h1*127))
  __shared__ __align__(16) char vA8[16 * H8];    // v = (1-h1^2)*u as i8 (scale su[m])
  __shared__ unsigned short h2A[16 * HS];        // h2 bf16 (GEMM3f A-operand)
  __shared__ unsigned short cbias[16 * HS];      // cond@W1c + b1, bf16 (per bijector)
  __shared__ __align__(16) char Bst[3][32768];   // staging ring: 3 x 32KB i8 panels
  __shared__ float f_s[16][64];
  __shared__ float l_row[16], ld_row[16], ldacc[16];
  __shared__ int sgu[16];                        // per-bijector rowmax |u| bits

  const int t = threadIdx.x;
  const int wave = t >> 6;
  const int lane = t & 63;
  const int lane15 = lane & 15;
  const int q8 = (lane >> 4) * 8;        // bf16 frag k-offset
  const int q16 = (lane >> 4) * 16;      // i8 frag k-offset (bytes)
  const int rowb = q8 >> 1;              // C/D row base
  const int row0 = blockIdx.x * 16;
  const int ws32 = wave * 32;            // N-slice base for N=512 GEMMs
  const int nt3 = wave & 3;              // N-tile for GEMM3f
  const int kb3 = (wave >> 2) * 128;     // K-slice base for GEMM3f
  const int tm = t >> 6, td = t & 63;    // (row, dim) element owned by this thread

  // swizzled 16B-granule read offset (same XOR for rows lane15 and 16+lane15)
  const int kk2b = q16 ^ (((lane15 >> 1) & 3) << 4);

  // RK4 state in registers (thread-private)
  float ycur, ytmp, yacc = 0.f;
  {
    float xv = x[(size_t)(row0 + tm) * 64 + td];
    ycur = xv; ytmp = xv;
  }
  if (t < 512) {
    int m = t >> 5, kk = t & 31;
    zA[m * ZS + 64 + kk] = (kk < 16) ? f2bf(cond[(size_t)(row0 + m) * 16 + kk]) : (unsigned short)0;
  }
  if (t < 16) { ld_row[t] = 0.f; l_row[t] = 0.f; }

  const float dt = 0.125f;
  const float w06 = dt / 6.f, w13 = dt / 3.f;
  const char* wsb = (const char*)ws;
  const float* wsf = (const float*)ws;

  for (int ib = 0; ib < 2; ++ib) {
    const unsigned short* W1f = ws + ib * 49152;
    const char* W2f8 = wsb + 196608 + ib * 262144;
    const unsigned short* W3f = ws + 360448 + ib * 32768;
    const unsigned short* W3b = ws + 425984 + ib * 32768;
    const unsigned short* W1u = ws + 491520 + ib * 32768;
    const unsigned short* W1c = ws + 559104 + ib * 16384;
    const float* w1tg = wsf + 312320 + ib * 512;
    const float* scf = (const float*)(wsb + 1114112) + ib * 512;
    const float* b1b = b1g + ib * 512;
    const float* b2b = b2g + ib * 512;
    const float* b3b = b3g + ib * 64;

    // ---- bijector prologue: stage eps (bf16, borrow zA), e3 + u + cbias GEMMs ----
    zA[tm * ZS + td] = f2bf(eps[((size_t)ib * 4096 + row0 + tm) * 64 + td]);
    if (t < 16) sgu[t] = 0;
    __syncthreads();

    float e3r[8], ur[8];
    {
      f32x4 a0 = {0,0,0,0}, a1 = {0,0,0,0};   // e3 = eps @ W3^T
      f32x4 u0 = {0,0,0,0}, u1 = {0,0,0,0};   // u  = eps @ W1y
      const unsigned short* ap = zA + lane15 * ZS + q8;
      const unsigned short* wp3 = W3b + (size_t)(ws32 + lane15) * 64 + q8;
      const unsigned short* wpu = W1u + (size_t)(ws32 + lane15) * 64 + q8;
      #pragma unroll
      for (int kk = 0; kk < 64; kk += 32) {
        short8 a = *(const short8*)(ap + kk);
        a0 = MFMA_B16(a, *(const short8*)(wp3 + kk),           a0);
        a1 = MFMA_B16(a, *(const short8*)(wp3 + 16 * 64 + kk), a1);
        u0 = MFMA_B16(a, *(const short8*)(wpu + kk),           u0);
        u1 = MFMA_B16(a, *(const short8*)(wpu + 16 * 64 + kk), u1);
      }
      #pragma unroll
      for (int rg = 0; rg < 4; ++rg) {
        e3r[rg] = a0[rg]; e3r[4 + rg] = a1[rg];
        ur[rg] = u0[rg];  ur[4 + rg] = u1[rg];
      }
      // per-row max|u| (exact per-bijector bound for the v quantization)
      #pragma unroll
      for (int rg = 0; rg < 4; ++rg) {
        float mr = fmaxf(fabsf(ur[rg]), fabsf(ur[4 + rg]));
        #pragma unroll
        for (int o = 1; o < 16; o <<= 1) mr = fmaxf(mr, __shfl_xor(mr, o));
        if (lane15 == 0) atomicMax(&sgu[rowb + rg], __float_as_int(mr));
      }
      // cbias = cond @ W1c + b1 (K=32; zA cols 64..95 hold cond, persistent since init;
      // W1c rows kk>=16 are zero so any junk in zA cols 80..95 is multiplied by 0)
      f32x4 c0v = {0,0,0,0}, c1v = {0,0,0,0};
      short8 acnd = *(const short8*)(zA + lane15 * ZS + 64 + q8);
      const unsigned short* wpc = W1c + (size_t)(ws32 + lane15) * 32 + q8;
      c0v = MFMA_B16(acnd, *(const short8*)wpc,             c0v);
      c1v = MFMA_B16(acnd, *(const short8*)(wpc + 16 * 32), c1v);
      #pragma unroll
      for (int tl = 0; tl < 2; ++tl) {
        int n = ws32 + tl * 16 + lane15;
        float bb = b1b[n];
        f32x4 cc = tl ? c1v : c0v;
        #pragma unroll
        for (int rg = 0; rg < 4; ++rg)
          cbias[(rowb + rg) * HS + n] = f2bf(cc[rg] + bb);
      }
    }
    __syncthreads();   // sgu+cbias complete; zA cols 0-63 about to be rewritten by P0

    float su_[4], qsv[4];
    #pragma unroll
    for (int rg = 0; rg < 4; ++rg) {
      float sg = fmaxf(__int_as_float(sgu[rowb + rg]), 1e-20f);
      su_[rg] = sg * INV2;       // folded w-dequant factor (x scf[n] later)
      qsv[rg] = 127.f / sg;
    }

    for (int it = 0; it < 32; ++it) {
      const int s = it & 3;
      const float te = (it >> 2) * dt + ((s == 0) ? 0.f : (s == 3) ? dt : 0.5f * dt);

      // ---- P0: deferred RK4 + logdet, z build, zero f_s; it==0: prefetch 2 panels ----
      if (it > 0) {
        int sp = (it - 1) & 3;
        float fv = f_s[tm][td] + b3b[td];
        if (sp == 0)      { yacc = ycur + w06 * fv; ytmp = ycur + 0.5f * dt * fv; }
        else if (sp == 1) { yacc += w13 * fv;       ytmp = ycur + 0.5f * dt * fv; }
        else if (sp == 2) { yacc += w13 * fv;       ytmp = ycur + dt * fv; }
        else              { float yn = yacc + w06 * fv; ycur = yn; ytmp = yn; }
      }
      zA[tm * ZS + td] = f2bf(ytmp);
      f_s[tm][td] = 0.f;
      if (t < 16) {
        if (it > 0) {
          int sp = (it - 1) & 3;
          float lv = l_row[t];
          if (sp == 0)      ldacc[t] = w06 * lv;
          else if (sp < 3)  ldacc[t] += w13 * lv;
          else              ld_row[t] += ldacc[t] + w06 * lv;
        }
        l_row[t] = 0.f;
      }
      if (it == 0) { ISSUE_STAGE(W2f8, 0, 0); ISSUE_STAGE(W2f8, 1, 1); }
      __syncthreads();

      // ---- P1: GEMM1 (bf16, K=64 over y): h1 = tanh(acc + cbias + te*w1t) ----
      {
        f32x4 a0 = {0,0,0,0}, a1 = {0,0,0,0};
        const unsigned short* ap = zA + lane15 * ZS + q8;
        const unsigned short* wp = W1f + (size_t)(ws32 + lane15) * 96 + q8;
        #pragma unroll
        for (int k0 = 0; k0 < 64; k0 += 32) {
          short8 a = *(const short8*)(ap + k0);
          a0 = MFMA_B16(a, *(const short8*)(wp + k0),           a0);
          a1 = MFMA_B16(a, *(const short8*)(wp + 16 * 96 + k0), a1);
        }
        #pragma unroll
        for (int tl = 0; tl < 2; ++tl) {
          int n = ws32 + tl * 16 + lane15;
          float wt = w1tg[n];
          f32x4 ac = tl ? a1 : a0;
          #pragma unroll
          for (int rg = 0; rg < 4; ++rg) {
            int off = (rowb + rg) * H8 + n;
            float pre = ac[rg] + bf2f(cbias[(rowb + rg) * HS + n]) + te * wt;
            float th = fast_tanh(pre);
            h1A8[off] = (char)__float2int_rn(th * 127.f);
            float v = (1.f - th * th) * ur[tl * 4 + rg];
            vA8[off] = (char)__float2int_rn(v * qsv[rg]);
          }
        }
      }
      __syncthreads();

      // ---- P2: staged dual i8 GEMM, delayed-issue ring (no order-pinning) ----
      {
        int4v ha0 = {0,0,0,0}, ha1 = {0,0,0,0}, wa0 = {0,0,0,0}, wa1 = {0,0,0,0};
        const char* aph = h1A8 + lane15 * H8;
        const char* apv = vA8 + lane15 * H8;
        #pragma unroll
        for (int ks = 0; ks < 8; ++ks) {
          // wait panel ks landed: newest pair in flight is p_{ks+1}; at ks=7 drain all
          if (ks < 7) asm volatile("s_waitcnt vmcnt(2)" ::: "memory");
          else        asm volatile("s_waitcnt vmcnt(0)" ::: "memory");
          const char* bq = &Bst[ks % 3][wave << 11];
          int4v ah = *(const int4v*)(aph + ks * 64 + q16);
          int4v av = *(const int4v*)(apv + ks * 64 + q16);
          int4v b0 = *(const int4v*)(bq + lane15 * 64 + kk2b);
          int4v b1 = *(const int4v*)(bq + (16 + lane15) * 64 + kk2b);
          if (ks < 6) {
            // WAR guard: slot (ks+2)%3 == (ks-1)%3 was read LAST iteration; DS retires
            // in-order, so lgkmcnt(4) (this iteration's 4 reads may remain) suffices.
            asm volatile("s_waitcnt lgkmcnt(4)" ::: "memory");
            ISSUE_STAGE(W2f8, ks + 2, (ks + 2) % 3);
          }
          ha0 = MFMA_I8(ah, b0, ha0);
          ha1 = MFMA_I8(ah, b1, ha1);
          wa0 = MFMA_I8(av, b0, wa0);
          wa1 = MFMA_I8(av, b1, wa1);
        }
        float p0 = 0.f, p1 = 0.f, p2 = 0.f, p3 = 0.f;
        #pragma unroll
        for (int tl = 0; tl < 2; ++tl) {
          int n = ws32 + tl * 16 + lane15;
          float bias = b2b[n];
          float dq = scf[n] * INV2;
          float dqw = scf[n];
          int4v hac = tl ? ha1 : ha0;
          int4v wac = tl ? wa1 : wa0;
          #pragma unroll
          for (int rg = 0; rg < 4; ++rg) {
            float h = fast_tanh((float)hac[rg] * dq + bias);
            h2A[(rowb + rg) * HS + n] = f2bf(h);
            float g2 = e3r[tl * 4 + rg] * (1.f - h * h);
            float w = (float)wac[rg] * dqw * su_[rg];
            float pc = g2 * w;
            if (rg == 0) p0 += pc; else if (rg == 1) p1 += pc;
            else if (rg == 2) p2 += pc; else p3 += pc;
          }
        }
        #pragma unroll
        for (int o = 1; o < 16; o <<= 1) {
          p0 += __shfl_xor(p0, o); p1 += __shfl_xor(p1, o);
          p2 += __shfl_xor(p2, o); p3 += __shfl_xor(p3, o);
        }
        if (lane15 == 0) {
          atomicAdd(&l_row[rowb + 0], p0); atomicAdd(&l_row[rowb + 1], p1);
          atomicAdd(&l_row[rowb + 2], p2); atomicAdd(&l_row[rowb + 3], p3);
        }
      }
      __syncthreads();

      // ---- P3: prefetch next-eval panels 0,1; GEMM3f (bf16): f += h2 @ W3f ----
      if (it < 31) { ISSUE_STAGE(W2f8, 0, 0); ISSUE_STAGE(W2f8, 1, 1); }
      {
        f32x4 c0 = {0,0,0,0};
        const unsigned short* ap3 = h2A + lane15 * HS + kb3 + q8;
        const unsigned short* wp3 = W3f + (size_t)(nt3 * 16 + lane15) * 512 + kb3 + q8;
        #pragma unroll
        for (int kk = 0; kk < 128; kk += 32)
          c0 = MFMA_B16(*(const short8*)(ap3 + kk), *(const short8*)(wp3 + kk), c0);
        #pragma unroll
        for (int rg = 0; rg < 4; ++rg)
          atomicAdd(&f_s[rowb + rg][nt3 * 16 + lane15], c0[rg]);
      }
      __syncthreads();
    }

    // ---- bijector finalize: last RK4 stage (s=3) + logdet stage ----
    {
      float fv = f_s[tm][td] + b3b[td];
      float yn = yacc + w06 * fv;
      ycur = yn; ytmp = yn;
    }
    if (t < 16) { ld_row[t] += ldacc[t] + w06 * l_row[t]; l_row[t] = 0.f; }
    __syncthreads();
  }

  out[(size_t)(row0 + tm) * 65 + td] = ycur;
  if (t < 16) out[(size_t)(row0 + t) * 65 + 64] = ld_row[t];
}

extern "C" void kernel_launch(void* const* d_in, const int* in_sizes, int n_in,
                              void* d_out, int out_size, void* d_ws, size_t ws_size,
                              hipStream_t stream) {
  (void)in_sizes; (void)n_in; (void)out_size; (void)ws_size;
  const float* x    = (const float*)d_in[0];
  const float* cond = (const float*)d_in[1];
  const float* eps  = (const float*)d_in[2];
  const float* W1   = (const float*)d_in[3];
  const float* b1   = (const float*)d_in[4];
  const float* W2   = (const float*)d_in[5];
  const float* b2   = (const float*)d_in[6];
  const float* W3   = (const float*)d_in[7];
  const float* b3   = (const float*)d_in[8];
  float* out = (float*)d_out;
  unsigned short* ws = (unsigned short*)d_ws;
  float* sc = (float*)((char*)ws + 1114112);

  prep_sc_init<<<4, 256, 0, stream>>>(sc);
  prep_scales<<<64, 256, 0, stream>>>(W2, sc);
  prep_w2<<<128, 256, 0, stream>>>(W2, ws);
  prep_rest<<<1284, 256, 0, stream>>>(W1, W3, ws);
  ffjord_mfma<<<256, 1024, 0, stream>>>(x, cond, eps, b1, b2, b3, ws, out);
}